// Round 4
// baseline (634.378 us; speedup 1.0000x reference)
//
#include <hip/hip_runtime.h>
#include <math.h>

#define EPSV 1e-5f
#define HD 128
#define IT 64
#define JT 32
#define WP 68
#define CCH 16
#define THR 256

typedef __attribute__((address_space(3))) uint32_t lds_u32_t;
typedef __attribute__((address_space(1))) uint32_t gbl_u32_t;
typedef __attribute__((ext_vector_type(8))) short bf16x8;
typedef __attribute__((ext_vector_type(4))) float f32x4;

__device__ __forceinline__ void async_copy16(const float* g, float* l) {
    __builtin_amdgcn_global_load_lds((const gbl_u32_t*)g, (lds_u32_t*)l, 16, 0, 0);
}

// stage a JT x HD fp32 tile (16 KB) global -> LDS via async DMA (256 threads)
__device__ __forceinline__ void stage_tile_async(const float* gsrc, float* lds, int t) {
    int wv = t >> 6, lane = t & 63;
#pragma unroll
    for (int it = 0; it < 4; ++it) {
        int c = it * 4 + wv;
        async_copy16(gsrc + c * 256 + lane * 4, lds + c * 256);
    }
}

// stage an 8 KB bf16 tile global -> LDS via async DMA (256 threads, 2 insts)
__device__ __forceinline__ void stage_8k(const void* g, void* l, int t) {
    const float* gf = (const float*)g; float* lf = (float*)l;
    async_copy16(gf + t * 4, lf + t * 4);
    async_copy16(gf + t * 4 + 1024, lf + t * 4 + 1024);
}

__device__ __forceinline__ unsigned int f2bf(float f) {
    return __builtin_bit_cast(unsigned int, f) >> 16;
}

// round-to-nearest-even fp32 -> bf16
__device__ __forceinline__ unsigned short rne_bf16(float f) {
    unsigned int u = __builtin_bit_cast(unsigned int, f);
    u += 0x7FFFu + ((u >> 16) & 1u);
    return (unsigned short)(u >> 16);
}

// ---------------- param structs ----------------
struct WprepP { const float *W, *a1, *a2; unsigned short* WT; float *wa1, *wa2; int K; };
struct XprepP { const float* X; unsigned short* Xbf; const float *wa1, *wa2;
                float *sa, *sb; int rows; };
struct GmfP   { const unsigned short *Xbf, *WT; unsigned short* hT; int N, tilesJ; };
struct AggP  { const unsigned int* mask; const float *sa, *sb, *sm; const unsigned short* hT;
               float* out; int N, tiles, tilesJ; };
struct CrossP{ const float *A, *src, *rs1; float *pp; int iN, jN, tiles, tps; };
struct MlpP  { const float *pp, *scale; int S; const float *W1, *b1, *W2, *b2, *res;
               float *out; int rows; };

// ---------------- normalization scale kernels ----------------

__global__ void colsum_part_k(const float* __restrict__ A, float* __restrict__ s1p,
                              int B, int NO, int NV) {
    int v = blockIdx.x * 256 + threadIdx.x;
    int c = blockIdx.y, b = blockIdx.z;
    if (v >= NV) return;
    int chunk = (NO + CCH - 1) / CCH;
    int o0 = c * chunk;
    int o1 = o0 + chunk; if (o1 > NO) o1 = NO;
    const float* Ab = A + (size_t)b * NO * NV + v;
    float s = 0.f;
    for (int o = o0; o < o1; ++o) s += Ab[(size_t)o * NV];
    s1p[((size_t)b * CCH + c) * NV + v] = s;
}

__global__ void colsum_fin_k(const float* __restrict__ s1p, float* __restrict__ rs1,
                             int B, int NV) {
    int idx = blockIdx.x * 256 + threadIdx.x;
    if (idx >= B * NV) return;
    int b = idx / NV, v = idx - b * NV;
    float s = 0.f;
    for (int c = 0; c < CCH; ++c) s += s1p[((size_t)b * CCH + c) * NV + v];
    rs1[idx] = 1.f / (s + EPSV);
}

__global__ void rowsum_inv_k(const float* __restrict__ A, const float* __restrict__ rs1,
                             float* __restrict__ rs2, int B, int NO, int NV) {
    int row = blockIdx.x * (blockDim.x >> 6) + (threadIdx.x >> 6);
    int lane = threadIdx.x & 63;
    if (row >= B * NO) return;
    int b = row / NO;
    const float* Ar = A + (size_t)row * NV;
    const float* r1 = rs1 + (size_t)b * NV;
    float s = 0.f;
    for (int v = lane; v < NV; v += 64) s += Ar[v] * r1[v];
    for (int off = 32; off; off >>= 1) s += __shfl_xor(s, off, 64);
    if (lane == 0) rs2[row] = 1.f / (s + EPSV);
}

// ---------------- adjacency bitmask generation (runs once, both layers reuse) ----
// maskT layout: [b][word][i] u32, bit(j&31) = adj[b][i][word*32+j&31] > 0.
// One thread builds one word from 8 coalesced float4 loads (128 B/thread).
// All index divisions are by template constants (magic-mul, no VALU div).
template<int N, int TILESJ>
__global__ __launch_bounds__(256)
void maskg_k(const float* __restrict__ adj, unsigned int* __restrict__ maskT) {
    int tid = blockIdx.x * 256 + threadIdx.x;
    int w = tid % TILESJ;
    int rowid = tid / TILESJ;                        // b*N + i
    if (rowid >= 8 * N) return;
    int b = rowid / N, i = rowid - b * N;
    int j0 = w * 32;
    const float* src = adj + (size_t)rowid * N + j0;
    unsigned int bits = 0u;
    if (j0 + 32 <= N) {
#pragma unroll
        for (int q = 0; q < 8; ++q) {
            float4 v = ((const float4*)src)[q];
            bits |= (v.x > 0.f ? 1u : 0u) << (q * 4 + 0);
            bits |= (v.y > 0.f ? 1u : 0u) << (q * 4 + 1);
            bits |= (v.z > 0.f ? 1u : 0u) << (q * 4 + 2);
            bits |= (v.w > 0.f ? 1u : 0u) << (q * 4 + 3);
        }
    } else {
#pragma unroll
        for (int r = 0; r < 32; ++r)
            if (j0 + r < N) bits |= (src[r] > 0.f ? 1u : 0u) << r;
    }
    maskT[((size_t)b * TILESJ + w) * N + i] = bits;
}

// ---------------- weight prep (runs once): WT[c][k] bf16 + wa1/wa2 = W @ a ----------
__global__ __launch_bounds__(256)
void wprep_k(WprepP p0, WprepP p1, WprepP p2, WprepP p3, int e0, int e1, int e2) {
    __shared__ float lw[32][129];
    __shared__ float a1s[128], a2s[128];
    int bid = blockIdx.x;
    const WprepP& P = bid < e0 ? p0 : bid < e1 ? p1 : bid < e2 ? p2 : p3;
    int lb = bid < e0 ? bid : bid < e1 ? bid - e0 : bid < e2 ? bid - e1 : bid - e2;
    int k0 = lb * 32, K = P.K;
    int t = threadIdx.x;
    if (t < 128) { a1s[t] = P.a1[t]; a2s[t] = P.a2[t]; }
    for (int idx = t; idx < 32 * 32; idx += 256) {   // float4 granularity
        int kk = idx >> 5, c4 = idx & 31;
        float4 v = ((const float4*)(P.W + (size_t)(k0 + kk) * 128))[c4];
        lw[kk][c4 * 4 + 0] = v.x; lw[kk][c4 * 4 + 1] = v.y;
        lw[kk][c4 * 4 + 2] = v.z; lw[kk][c4 * 4 + 3] = v.w;
    }
    __syncthreads();
    // wa1/wa2: 8 lanes per k-row
    int kk = t >> 3, g = t & 7;
    float s1 = 0.f, s2 = 0.f;
    for (int c = g; c < 128; c += 8) {
        float w = lw[kk][c];
        s1 = fmaf(w, a1s[c], s1);
        s2 = fmaf(w, a2s[c], s2);
    }
    s1 += __shfl_xor(s1, 1, 64); s1 += __shfl_xor(s1, 2, 64); s1 += __shfl_xor(s1, 4, 64);
    s2 += __shfl_xor(s2, 1, 64); s2 += __shfl_xor(s2, 2, 64); s2 += __shfl_xor(s2, 4, 64);
    if (g == 0) { P.wa1[k0 + kk] = s1; P.wa2[k0 + kk] = s2; }
    // transposed bf16 store: WT[c][k]
    for (int idx = t; idx < 4096; idx += 256) {
        int c = idx >> 5, k = idx & 31;
        P.WT[(size_t)c * K + k0 + k] = rne_bf16(lw[k][c]);
    }
}

// ---------------- X prep: Xbf = rne_bf16(X); sa = X.wa1, sb = X.wa2 (exact fp32) ----
template<int K>
__device__ void xprep_body(const XprepP& P, int lb) {
    int t = threadIdx.x, wv = t >> 6, lane = t & 63;
    int row = lb * 4 + wv;
    if (row >= P.rows) return;
    const float4* x4 = (const float4*)(P.X + (size_t)row * K);
    const float4* w14 = (const float4*)P.wa1;
    const float4* w24 = (const float4*)P.wa2;
    unsigned short* xb = P.Xbf + (size_t)row * K;
    float s1 = 0.f, s2 = 0.f;
    constexpr int K4 = K / 4;
    constexpr int NI = (K4 + 63) / 64;
#pragma unroll
    for (int i = 0; i < NI; ++i) {
        int k4 = i * 64 + lane;
        if ((K4 % 64 == 0) || (k4 < K4)) {
            float4 x = x4[k4];
            float4 a = w14[k4];
            float4 b = w24[k4];
            s1 += x.x * a.x + x.y * a.y + x.z * a.z + x.w * a.w;
            s2 += x.x * b.x + x.y * b.y + x.z * b.z + x.w * b.w;
            ushort4 p = make_ushort4(rne_bf16(x.x), rne_bf16(x.y),
                                     rne_bf16(x.z), rne_bf16(x.w));
            *(ushort4*)(xb + (size_t)k4 * 4) = p;
        }
    }
#pragma unroll
    for (int off = 32; off; off >>= 1) {
        s1 += __shfl_xor(s1, off, 64);
        s2 += __shfl_xor(s2, off, 64);
    }
    if (lane == 0) { P.sa[row] = s1; P.sb[row] = s2; }
}

template<int KV, int KO>
__global__ __launch_bounds__(256)
void xprep2_k(XprepP V, XprepP O, int GV) {
    int bid = blockIdx.x;
    if (bid < GV) xprep_body<KV>(V, bid);
    else          xprep_body<KO>(O, bid - GV);
}

// ---------------- MFMA h-GEMM producing hT directly (bank-swizzled layout) --------
// D[m=c][n=jl] = sum_k WT[c][k] * Xbf[row0+jl][k]  via mfma_f32_16x16x32_bf16.
// hT tile layout is SWIZZLED: element (c, jl) lives at ushort index
//   c*32 + (jl ^ (((c>>1)&3)<<3))
// so agg's per-quad ds_read_b128 of the 64-B-stride row tile is bank-conflict-free
// while the global_load_lds DMA stays linear (swizzle baked into global layout).
template<int K>
__device__ void gmf_body(const GmfP& P, int lb) {
    int tilesJ = P.tilesJ, N = P.N;
    int b = lb / tilesJ, jt = lb - b * tilesJ;
    int t = threadIdx.x, wv = t >> 6, lane = t & 63;
    int ml = lane & 15, quad = lane >> 4;
    const unsigned short* xb = P.Xbf + ((size_t)b * N + (size_t)jt * 32) * K;
    const unsigned short* wt0 = P.WT + (size_t)(wv * 32 + ml) * K;
    const unsigned short* wt1 = wt0 + (size_t)16 * K;
    const unsigned short* xb0 = xb + (size_t)ml * K;
    const unsigned short* xb1 = xb + (size_t)(16 + ml) * K;
    f32x4 acc00 = {0.f, 0.f, 0.f, 0.f}, acc01 = acc00, acc10 = acc00, acc11 = acc00;
#pragma unroll 4
    for (int kt = 0; kt < K / 32; ++kt) {
        int kk = kt * 32 + quad * 8;
        bf16x8 a0 = *(const bf16x8*)(wt0 + kk);
        bf16x8 a1 = *(const bf16x8*)(wt1 + kk);
        bf16x8 b0 = *(const bf16x8*)(xb0 + kk);
        bf16x8 b1 = *(const bf16x8*)(xb1 + kk);
        acc00 = __builtin_amdgcn_mfma_f32_16x16x32_bf16(a0, b0, acc00, 0, 0, 0);
        acc01 = __builtin_amdgcn_mfma_f32_16x16x32_bf16(a0, b1, acc01, 0, 0, 0);
        acc10 = __builtin_amdgcn_mfma_f32_16x16x32_bf16(a1, b0, acc10, 0, 0, 0);
        acc11 = __builtin_amdgcn_mfma_f32_16x16x32_bf16(a1, b1, acc11, 0, 0, 0);
    }
    unsigned short* hb = P.hT + (size_t)(b * tilesJ + jt) * 4096;
    int nvalid = N - jt * 32; if (nvalid > 32) nvalid = 32;
    bool ok0 = ml < nvalid, ok1 = (16 + ml) < nvalid;
    int c0 = wv * 32 + quad * 4;
#pragma unroll
    for (int r = 0; r < 4; ++r) {
        int ca = c0 + r, cb = c0 + 16 + r;
        int swa = ((ca >> 1) & 3) << 3, swb = ((cb >> 1) & 3) << 3;
        hb[ca * 32 + (ml ^ swa)]        = ok0 ? rne_bf16(acc00[r]) : 0;
        hb[ca * 32 + ((16 + ml) ^ swa)] = ok1 ? rne_bf16(acc01[r]) : 0;
        hb[cb * 32 + (ml ^ swb)]        = ok0 ? rne_bf16(acc10[r]) : 0;
        hb[cb * 32 + ((16 + ml) ^ swb)] = ok1 ? rne_bf16(acc11[r]) : 0;
    }
}

template<int KV, int KO>
__global__ __launch_bounds__(256)
void gmf2_k(GmfP V, GmfP O, int GV) {
    int bid = blockIdx.x;
    if (bid < GV) gmf_body<KV>(V, bid);
    else          gmf_body<KO>(O, bid - GV);
}

// ---------------- fused per-batch sb max ----------------
__global__ __launch_bounds__(256)
void sbmax2_k(const float* __restrict__ sbV, float* __restrict__ smV,
              const float* __restrict__ sbO, float* __restrict__ smO,
              int NV, int NO) {
    __shared__ float red[256];
    int b0 = blockIdx.x, t = threadIdx.x;
    const float* sb; float* out; int N;
    if (b0 < 8) { sb = sbV + (size_t)b0 * NV; out = smV + b0; N = NV; }
    else        { sb = sbO + (size_t)(b0 - 8) * NO; out = smO + (b0 - 8); N = NO; }
    float m = -INFINITY;
    for (int j = t; j < N; j += 256) m = fmaxf(m, sb[j]);
    red[t] = m; __syncthreads();
    for (int s = 128; s; s >>= 1) {
        if (t < s) red[t] = fmaxf(red[t], red[t + s]);
        __syncthreads();
    }
    if (t == 0) *out = red[0];
}

// ---------------- MFMA GAT aggregation, FULL-ROW (vis+obj fused) ----------------
// Each block owns one 64-row i-tile and walks ALL tilesJ j-tiles, so z is
// complete in-block: the epilogue divides by z, applies relu, and writes the
// FINAL GAT output (no fin pass, no partial-sum traffic). adj consumed as a
// 1-bit mask staged in LDS; hT DMA depth-2 over 3 buffers with counted vmcnt.
struct SharedAggM {
    unsigned short hsT[3][128][32];    // [c][jl-swz] bf16, DMA'd from hT (3-deep)
    unsigned short wsA[2][4][64][8];   // A-fragment order per wave
    unsigned int mask_s[48][64];       // [tile][row] adjacency bits
    float sb_s[48 * 32];               // sb for the whole j-range
    float sa_s[IT], m_s[IT], z_s[IT];
};

__device__ void agg_body(SharedAggM& sm, const AggP& P, int lbid) {
    int tiles = P.tiles;
    int b = lbid / tiles;
    int i0 = (lbid - b * tiles) * IT;
    int N = P.N;
    int T = P.tilesJ;
    int t = threadIdx.x;
    if (t < IT) {
        int i = i0 + t;
        float s = (i < N) ? P.sa[(size_t)b * N + i] : 0.f;
        sm.sa_s[t] = s;
        float e = s + P.sm[b];
        sm.m_s[t] = e > 0.f ? e : 0.2f * e;
    }
    // stage adjacency bitmask for all tiles: mask_s[w][r], coalesced in r
    for (int idx = t; idx < (T << 6); idx += 256) {
        int w = idx >> 6, r = idx & 63;
        int ir = i0 + r;
        sm.mask_s[w][r] = (ir < N)
            ? P.mask[((size_t)b * T + w) * N + ir] : 0u;
    }
    // stage sb for the whole row
    const float* sbb = P.sb + (size_t)b * N;
    for (int idx = t; idx < (T << 5); idx += 256) {
        sm.sb_s[idx] = (idx < N) ? sbb[idx] : 0.f;
    }
    __syncthreads();
    // prologue: DMA tiles 0 and 1 (depth-2)
    const unsigned short* hTb = P.hT + (size_t)b * T * 4096;
    stage_8k(hTb, &sm.hsT[0][0][0], t);
    stage_8k(hTb + 4096, &sm.hsT[1][0][0], t);

    int wv = t >> 6, lane = t & 63;
    // w-producer role: thread owns row il, j-offsets {j4..j4+3, j4+16..j4+19}
    int il = t >> 2, j4 = (t & 3) * 4;
    int q0 = j4 >> 3, i0w = j4 & 7, wrow = il & 15;
    // MFMA consumer role (nq2 folds the hT layout swizzle: granule ^ row[2:1])
    int nquad = lane >> 4, nlow = lane & 15;
    int nq2 = (nquad ^ ((nlow >> 1) & 3)) * 8;
    f32x4 acc[8];
#pragma unroll
    for (int nt = 0; nt < 8; ++nt)
#pragma unroll
        for (int r = 0; r < 4; ++r) acc[nt][r] = 0.f;
    float zacc = 0.f;
    const float4* sb4 = (const float4*)sm.sb_s;
    for (int tt = 0; tt < T; ++tt) {
        int cur = tt - (tt / 3) * 3;                 // tt % 3
        unsigned int mw = sm.mask_s[tt][il];
        float4 sA = sb4[tt * 8 + (t & 3)];
        float4 sB = sb4[tt * 8 + (t & 3) + 4];
        float sai = sm.sa_s[il], m = sm.m_s[il];
#pragma unroll
        for (int k = 0; k < 2; ++k) {
            float sv[4];
            { float4 s4 = k ? sB : sA; sv[0] = s4.x; sv[1] = s4.y; sv[2] = s4.z; sv[3] = s4.w; }
            float w_[4];
#pragma unroll
            for (int r = 0; r < 4; ++r) {
                float e = sai + sv[r];
                e = e > 0.f ? e : 0.2f * e;
                float ww = __expf(e - m);
                ww = ((mw >> (j4 + k * 16 + r)) & 1u) ? ww : 0.f;
                zacc += ww;
                w_[r] = ww;
            }
            unsigned int lo = f2bf(w_[0]) | (__builtin_bit_cast(unsigned int, w_[1]) & 0xFFFF0000u);
            unsigned int hi = f2bf(w_[2]) | (__builtin_bit_cast(unsigned int, w_[3]) & 0xFFFF0000u);
            *(uint2*)&sm.wsA[tt & 1][wv][wrow + 16 * (q0 + 2 * k)][i0w] = make_uint2(lo, hi);
        }
        // drain own DMA(tt) [keep DMA(tt+1) flying] + wsA writes, then rendezvous
        if (tt + 1 < T) asm volatile("s_waitcnt vmcnt(2) lgkmcnt(0)" ::: "memory");
        else            asm volatile("s_waitcnt vmcnt(0) lgkmcnt(0)" ::: "memory");
        __builtin_amdgcn_s_barrier();
        asm volatile("" ::: "memory");
        if (tt + 2 < T) {
            int nb = tt + 2; nb -= (nb / 3) * 3;
            stage_8k(hTb + (size_t)(tt + 2) * 4096, &sm.hsT[nb][0][0], t);
        }
        bf16x8 afrag = *(const bf16x8*)&sm.wsA[tt & 1][wv][lane][0];
#pragma unroll
        for (int nt = 0; nt < 8; ++nt) {
            bf16x8 bfrag = *(const bf16x8*)&sm.hsT[cur][nt * 16 + nlow][nq2];
            acc[nt] = __builtin_amdgcn_mfma_f32_16x16x32_bf16(afrag, bfrag, acc[nt], 0, 0, 0);
        }
    }
    // z: reduce over the 4 threads sharing row il, publish to LDS
    zacc += __shfl_xor(zacc, 1, 64);
    zacc += __shfl_xor(zacc, 2, 64);
    if ((t & 3) == 0) sm.z_s[il] = zacc;
    __syncthreads();
    // epilogue: divide by z, relu, store FINAL output
    float inv[4];
#pragma unroll
    for (int r = 0; r < 4; ++r) inv[r] = 1.f / sm.z_s[wv * 16 + nquad * 4 + r];
    float* outb = P.out + (size_t)b * N * HD;
#pragma unroll
    for (int nt = 0; nt < 8; ++nt)
#pragma unroll
        for (int r = 0; r < 4; ++r) {
            int row = i0 + wv * 16 + nquad * 4 + r;
            if (row < N)
                outb[(size_t)row * HD + nt * 16 + nlow] = fmaxf(acc[nt][r] * inv[r], 0.f);
        }
}

__global__ __launch_bounds__(256)
void agg2_k(AggP V, AggP O, int GVb) {
    __shared__ SharedAggM sm;
    int bid = blockIdx.x;
    if (bid < GVb) agg_body(sm, V, bid);
    else           agg_body(sm, O, bid - GVb);
}

// ---------------- 256-thread fp32 tile FMA (cross kernels) ----------------
__device__ __forceinline__ void tile_fma256(const float (*hs)[HD], const float (*ws)[WP],
                                            int rg, int c0, float acc[4][8]) {
#pragma unroll 8
    for (int jl = 0; jl < JT; ++jl) {
        float4 h0 = *(const float4*)&hs[jl][c0];
        float4 h1 = *(const float4*)&hs[jl][c0 + 64];
        float4 w4 = *(const float4*)&ws[jl][rg * 4];
        float wq[4] = {w4.x, w4.y, w4.z, w4.w};
#pragma unroll
        for (int q = 0; q < 4; ++q) {
            float w = wq[q];
            acc[q][0] = fmaf(w, h0.x, acc[q][0]);
            acc[q][1] = fmaf(w, h0.y, acc[q][1]);
            acc[q][2] = fmaf(w, h0.z, acc[q][2]);
            acc[q][3] = fmaf(w, h0.w, acc[q][3]);
            acc[q][4] = fmaf(w, h1.x, acc[q][4]);
            acc[q][5] = fmaf(w, h1.y, acc[q][5]);
            acc[q][6] = fmaf(w, h1.z, acc[q][6]);
            acc[q][7] = fmaf(w, h1.w, acc[q][7]);
        }
    }
}

__device__ __forceinline__ void part_store256(float* __restrict__ pp, size_t base,
                                              int i0, int N, int rg, int c0,
                                              float acc[4][8]) {
#pragma unroll
    for (int q = 0; q < 4; ++q) {
        int i = i0 + rg * 4 + q;
        if (i >= N) continue;
        float* op = pp + base + (size_t)i * HD;
        *(float4*)&op[c0]      = make_float4(acc[q][0], acc[q][1], acc[q][2], acc[q][3]);
        *(float4*)&op[c0 + 64] = make_float4(acc[q][4], acc[q][5], acc[q][6], acc[q][7]);
    }
}

struct SharedTile { float hs[2][JT][HD]; float ws[2][JT][WP]; };

// ---------------- fused cross (vo + ov), pipelined fp32 ----------------
__device__ void cross_vo_body(SharedTile& sm, const CrossP& P, int lbid) {
    int tiles = P.tiles;
    int split = lbid / (8 * tiles);
    int rem = lbid - split * 8 * tiles;
    int b = rem / tiles;
    int i0 = (rem - b * tiles) * IT;
    int NVl = P.iN, NOl = P.jN;
    int j_begin = split * P.tps * JT;
    if (j_begin >= NOl) return;
    int j_end = j_begin + P.tps * JT;
    if (j_end > NOl) j_end = NOl;
    int T = (j_end - j_begin + JT - 1) / JT;
    int t = threadIdx.x;
    int rg = t >> 4, c0 = (t & 15) * 4;
    int il = t & 63, jlb = t >> 6;
    float acc[4][8];
#pragma unroll
    for (int q = 0; q < 4; ++q)
#pragma unroll
        for (int x = 0; x < 8; ++x) acc[q][x] = 0.f;
    const float* Ab = P.A + (size_t)b * NOl * NVl;
    const float* srcb = P.src + (size_t)b * NOl * HD;
    int v = i0 + il;
    float w8[8];
    stage_tile_async(srcb + (size_t)j_begin * HD, &sm.hs[0][0][0], t);
#pragma unroll
    for (int k = 0; k < 8; ++k) {
        int o = j_begin + jlb + k * 4;
        w8[k] = (v < NVl && o < NOl) ? Ab[(size_t)o * NVl + v] : 0.f;
    }
    for (int tt = 0; tt < T; ++tt) {
        int cur = tt & 1;
#pragma unroll
        for (int k = 0; k < 8; ++k) sm.ws[cur][jlb + k * 4][il] = w8[k];
        __syncthreads();
        if (tt + 1 < T) {
            int jn = j_begin + (tt + 1) * JT;
            stage_tile_async(srcb + (size_t)jn * HD, &sm.hs[1 - cur][0][0], t);
#pragma unroll
            for (int k = 0; k < 8; ++k) {
                int o = jn + jlb + k * 4;
                w8[k] = (v < NVl && o < NOl) ? Ab[(size_t)o * NVl + v] : 0.f;
            }
        }
        tile_fma256(sm.hs[cur], sm.ws[cur], rg, c0, acc);
    }
    size_t rowsTot = (size_t)8 * NVl;
    part_store256(P.pp, ((size_t)split * rowsTot + (size_t)b * NVl) * HD, i0, NVl, rg, c0, acc);
}

__device__ void cross_ov_body(SharedTile& sm, const CrossP& P, int lbid) {
    int tiles = P.tiles;
    int split = lbid / (8 * tiles);
    int rem = lbid - split * 8 * tiles;
    int b = rem / tiles;
    int i0 = (rem - b * tiles) * IT;
    int NOl = P.iN, NVl = P.jN;
    int j_begin = split * P.tps * JT;
    if (j_begin >= NVl) return;
    int j_end = j_begin + P.tps * JT;
    if (j_end > NVl) j_end = NVl;
    int T = (j_end - j_begin + JT - 1) / JT;
    int t = threadIdx.x;
    int rg = t >> 4, c0 = (t & 15) * 4;
    int il = t >> 2, j4 = (t & 3) * 4;
    float acc[4][8];
#pragma unroll
    for (int q = 0; q < 4; ++q)
#pragma unroll
        for (int x = 0; x < 8; ++x) acc[q][x] = 0.f;
    const float* Ab = P.A + (size_t)b * NOl * NVl;
    const float* srcb = P.src + (size_t)b * NVl * HD;
    const float* r1b = P.rs1 + (size_t)b * NVl;
    int orow = i0 + il;
    float4 a4[2], r4[2];
    stage_tile_async(srcb + (size_t)j_begin * HD, &sm.hs[0][0][0], t);
#pragma unroll
    for (int k = 0; k < 2; ++k) {
        int vv = j_begin + j4 + k * 16;
        float4 av = make_float4(0.f,0.f,0.f,0.f), rv = make_float4(0.f,0.f,0.f,0.f);
        if (orow < NOl) {
            if (vv + 3 < NVl) {
                av = *(const float4*)&Ab[(size_t)orow * NVl + vv];
                rv = *(const float4*)&r1b[vv];
            } else {
                float* ap = (float*)&av; float* rp = (float*)&rv;
                for (int r = 0; r < 4; ++r)
                    if (vv + r < NVl) { ap[r] = Ab[(size_t)orow * NVl + vv + r]; rp[r] = r1b[vv + r]; }
            }
        }
        a4[k] = av; r4[k] = rv;
    }
    for (int tt = 0; tt < T; ++tt) {
        int cur = tt & 1;
#pragma unroll
        for (int k = 0; k < 2; ++k) {
            float wv[4] = {a4[k].x * r4[k].x, a4[k].y * r4[k].y,
                           a4[k].z * r4[k].z, a4[k].w * r4[k].w};
#pragma unroll
            for (int r = 0; r < 4; ++r) sm.ws[cur][j4 + r + k * 16][il] = wv[r];
        }
        __syncthreads();
        if (tt + 1 < T) {
            int jn = j_begin + (tt + 1) * JT;
            stage_tile_async(srcb + (size_t)jn * HD, &sm.hs[1 - cur][0][0], t);
#pragma unroll
            for (int k = 0; k < 2; ++k) {
                int vv = jn + j4 + k * 16;
                float4 av = make_float4(0.f,0.f,0.f,0.f), rv = make_float4(0.f,0.f,0.f,0.f);
                if (orow < NOl) {
                    if (vv + 3 < NVl) {
                        av = *(const float4*)&Ab[(size_t)orow * NVl + vv];
                        rv = *(const float4*)&r1b[vv];
                    } else {
                        float* ap = (float*)&av; float* rp = (float*)&rv;
                        for (int r = 0; r < 4; ++r)
                            if (vv + r < NVl) { ap[r] = Ab[(size_t)orow * NVl + vv + r]; rp[r] = r1b[vv + r]; }
                    }
                }
                a4[k] = av; r4[k] = rv;
            }
        }
        tile_fma256(sm.hs[cur], sm.ws[cur], rg, c0, acc);
    }
    size_t rowsTot = (size_t)8 * NOl;
    part_store256(P.pp, ((size_t)split * rowsTot + (size_t)b * NOl) * HD, i0, NOl, rg, c0, acc);
}

__global__ __launch_bounds__(256)
void cross2_k(CrossP VO, CrossP OV, int GVOb) {
    __shared__ SharedTile sm;
    int bid = blockIdx.x;
    if (bid < GVOb) cross_vo_body(sm, VO, bid);
    else            cross_ov_body(sm, OV, bid - GVOb);
}

// ---------------- fused MLP: out = (relu(x@W1+b1))@W2 + b2 + res ----------------
__global__ __launch_bounds__(128)
void mlp2_k(MlpP V, MlpP O, int GVb) {
    __shared__ float xs[8][HD];
    __shared__ float hh[8][HD];
    int bid = blockIdx.x;
    const MlpP& P = (bid < GVb) ? V : O;
    int row0 = ((bid < GVb) ? bid : bid - GVb) * 8;
    int rows = P.rows;
    int t = threadIdx.x;
    for (int l = t; l < 8 * 32; l += 128) {
        int r = l >> 5, c4 = l & 31;
        int row = row0 + r;
        float4 v = make_float4(0.f, 0.f, 0.f, 0.f);
        if (row < rows) {
            for (int s = 0; s < P.S; ++s) {
                float4 p = ((const float4*)P.pp)[((size_t)s * rows + row) * 32 + c4];
                v.x += p.x; v.y += p.y; v.z += p.z; v.w += p.w;
            }
            float sc = P.scale[row];
            v.x *= sc; v.y *= sc; v.z *= sc; v.w *= sc;
        }
        ((float4*)&xs[r][0])[c4] = v;
    }
    __syncthreads();
    int wv = t >> 6, tt = t & 63, rb = wv * 4;
    float a0[4] = {0.f, 0.f, 0.f, 0.f}, a1v[4] = {0.f, 0.f, 0.f, 0.f};
#pragma unroll 4
    for (int k = 0; k < HD; ++k) {
        float w0 = P.W1[(size_t)k * HD + tt];
        float w1 = P.W1[(size_t)k * HD + tt + 64];
#pragma unroll
        for (int r = 0; r < 4; ++r) {
            float x = xs[rb + r][k];
            a0[r] = fmaf(x, w0, a0[r]);
            a1v[r] = fmaf(x, w1, a1v[r]);
        }
    }
    float bb0 = P.b1[tt], bb1 = P.b1[tt + 64];
#pragma unroll
    for (int r = 0; r < 4; ++r) {
        hh[rb + r][tt]      = fmaxf(a0[r] + bb0, 0.f);
        hh[rb + r][tt + 64] = fmaxf(a1v[r] + bb1, 0.f);
    }
    __syncthreads();
    float c0a[4] = {0.f, 0.f, 0.f, 0.f}, c1a[4] = {0.f, 0.f, 0.f, 0.f};
#pragma unroll 4
    for (int k = 0; k < HD; ++k) {
        float w0 = P.W2[(size_t)k * HD + tt];
        float w1 = P.W2[(size_t)k * HD + tt + 64];
#pragma unroll
        for (int r = 0; r < 4; ++r) {
            float x = hh[rb + r][k];
            c0a[r] = fmaf(x, w0, c0a[r]);
            c1a[r] = fmaf(x, w1, c1a[r]);
        }
    }
    float d0 = P.b2[tt], d1 = P.b2[tt + 64];
#pragma unroll
    for (int r = 0; r < 4; ++r) {
        int row = row0 + rb + r;
        if (row >= rows) continue;
        P.out[(size_t)row * HD + tt]      = c0a[r] + d0 + P.res[(size_t)row * HD + tt];
        P.out[(size_t)row * HD + tt + 64] = c1a[r] + d1 + P.res[(size_t)row * HD + tt + 64];
    }
}

// ---------------- output projection ----------------
template<int RELU, int BIAS, int RES>
__global__ __launch_bounds__(128)
void linear_k(const float* __restrict__ X, const float* __restrict__ W,
              const float* __restrict__ bias, const float* __restrict__ res,
              float* __restrict__ out, int rows, int K, int Dout) {
    __shared__ float xs[4][512];
    int row0 = blockIdx.x * 4;
    int t = threadIdx.x;
    int K4 = K >> 2;
    for (int l = t; l < 4 * K4; l += 128) {
        int r = l / K4, c4 = l - r * K4;
        float4 val = make_float4(0.f, 0.f, 0.f, 0.f);
        if (row0 + r < rows) val = ((const float4*)(X + (size_t)(row0 + r) * K))[c4];
        ((float4*)&xs[r][0])[c4] = val;
    }
    __syncthreads();
    int chunk = Dout < 256 ? Dout : 256;
    int half = chunk >> 1;
    if (t >= half) return;
    int c0 = blockIdx.y * chunk + t;
    int c1 = c0 + half;
    float a00 = 0, a01 = 0, a02 = 0, a03 = 0, a10 = 0, a11 = 0, a12 = 0, a13 = 0;
#pragma unroll 4
    for (int k = 0; k < K; ++k) {
        float w0 = W[(size_t)k * Dout + c0];
        float w1 = W[(size_t)k * Dout + c1];
        float x0 = xs[0][k], x1 = xs[1][k], x2 = xs[2][k], x3 = xs[3][k];
        a00 = fmaf(x0, w0, a00); a01 = fmaf(x1, w0, a01);
        a02 = fmaf(x2, w0, a02); a03 = fmaf(x3, w0, a03);
        a10 = fmaf(x0, w1, a10); a11 = fmaf(x1, w1, a11);
        a12 = fmaf(x2, w1, a12); a13 = fmaf(x3, w1, a13);
    }
    float accs[2][4] = {{a00, a01, a02, a03}, {a10, a11, a12, a13}};
    int cs[2] = {c0, c1};
    for (int h = 0; h < 2; ++h) {
        float bv = BIAS ? bias[cs[h]] : 0.f;
        for (int r = 0; r < 4; ++r) {
            int row = row0 + r;
            if (row >= rows) continue;
            float v = accs[h][r] + bv;
            if (RES) v += res[(size_t)row * Dout + cs[h]];
            if (RELU) v = fmaxf(v, 0.f);
            out[(size_t)row * Dout + cs[h]] = v;
        }
    }
}

// ---------------- host launcher ----------------
extern "C" void kernel_launch(void* const* d_in, const int* in_sizes, int n_in,
                              void* d_out, int out_size, void* d_ws, size_t ws_size,
                              hipStream_t stream) {
    const int B = 8, NV = 500, NO = 1500, DV = 512, DO = 32;
    const float* vis_memory = (const float*)d_in[0];
    const float* obj_memory = (const float*)d_in[1];
    const float* vis_adj    = (const float*)d_in[2];
    const float* obj_adj    = (const float*)d_in[3];
    const float* A_OV       = (const float*)d_in[4];
    const float* Wv1  = (const float*)d_in[5];
    const float* av1a = (const float*)d_in[6];
    const float* av1b = (const float*)d_in[7];
    const float* Wv2  = (const float*)d_in[8];
    const float* av2a = (const float*)d_in[9];
    const float* av2b = (const float*)d_in[10];
    const float* Wo1  = (const float*)d_in[11];
    const float* ao1a = (const float*)d_in[12];
    const float* ao1b = (const float*)d_in[13];
    const float* Wo2  = (const float*)d_in[14];
    const float* ao2a = (const float*)d_in[15];
    const float* ao2b = (const float*)d_in[16];
    const float* g2o_W1 = (const float*)d_in[17];
    const float* g2o_b1 = (const float*)d_in[18];
    const float* g2o_W2 = (const float*)d_in[19];
    const float* g2o_b2 = (const float*)d_in[20];
    const float* o2g_W1 = (const float*)d_in[21];
    const float* o2g_b1 = (const float*)d_in[22];
    const float* o2g_W2 = (const float*)d_in[23];
    const float* o2g_b2 = (const float*)d_in[24];
    const float* img_W = (const float*)d_in[25];
    const float* img_b = (const float*)d_in[26];
    const float* obj_W = (const float*)d_in[27];
    const float* obj_b = (const float*)d_in[28];

    const int tilesJV = 16, tilesJO = 47;            // ceil(N/32)

    float* wsp = (float*)d_ws;
    size_t off = 0;
    auto alloc = [&](size_t n) { float* p = wsp + off; off += (n + 3) & ~(size_t)3; return p; };
    float* rs1   = alloc(B * NV);
    float* rs2   = alloc(B * NO);
    float* saV   = alloc(B * NV);
    float* sbV   = alloc(B * NV);
    float* smV   = alloc(B);
    float* saO   = alloc(B * NO);
    float* sbO   = alloc(B * NO);
    float* smO   = alloc(B);
    float* s1p   = alloc((size_t)B * CCH * NV);
    // adjacency bitmasks (transposed [b][word][i], u32)
    unsigned int* maskV = (unsigned int*)alloc((size_t)B * tilesJV * NV);
    unsigned int* maskO = (unsigned int*)alloc((size_t)B * tilesJO * NO);
    // weight-prep outputs (bf16 transposed W + score vectors)
    unsigned short* WTv1 = (unsigned short*)alloc(128 * 512 / 2);
    unsigned short* WTo1 = (unsigned short*)alloc(128 * 32 / 2);
    unsigned short* WTv2 = (unsigned short*)alloc(128 * 128 / 2);
    unsigned short* WTo2 = (unsigned short*)alloc(128 * 128 / 2);
    float* wav1a = alloc(512); float* wav1b = alloc(512);
    float* wao1a = alloc(32);  float* wao1b = alloc(32);
    float* wav2a = alloc(128); float* wav2b = alloc(128);
    float* wao2a = alloc(128); float* wao2b = alloc(128);
    // bf16 X buffers (max over layers: vis 4000x512, obj 12000x128)
    unsigned short* XbfV = (unsigned short*)alloc((size_t)B * NV * 512 / 2);
    unsigned short* XbfO = (unsigned short*)alloc((size_t)B * NO * 128 / 2);
    unsigned short* hTv = (unsigned short*)alloc((size_t)B * tilesJV * 4096 / 2);
    unsigned short* hTo = (unsigned short*)alloc((size_t)B * tilesJO * 4096 / 2);
    float* v1    = alloc((size_t)B * NV * HD);
    float* o1    = alloc((size_t)B * NO * HD);
    float* visb  = alloc((size_t)B * NV * HD);
    float* objb  = alloc((size_t)B * NO * HD);
    float* ppV   = alloc((size_t)8 * B * NV * HD);
    float* ppO   = alloc((size_t)4 * B * NO * HD);
    alloc(16384);                                    // tail pad for async/OOB reads

    // weight prep (once): 16 + 1 + 4 + 4 = 25 blocks
    {
        WprepP w0{Wv1, av1a, av1b, WTv1, wav1a, wav1b, DV};
        WprepP w1{Wo1, ao1a, ao1b, WTo1, wao1a, wao1b, DO};
        WprepP w2{Wv2, av2a, av2b, WTv2, wav2a, wav2b, HD};
        WprepP w3{Wo2, ao2a, ao2b, WTo2, wao2a, wao2b, HD};
        wprep_k<<<25, 256, 0, stream>>>(w0, w1, w2, w3, 16, 17, 21);
    }
    // adjacency bitmasks (once, reused by both layers); word-per-thread, vectorized
    maskg_k<500, 16><<<(8 * 500 * 16 + 255) / 256, 256, 0, stream>>>(vis_adj, maskV);
    maskg_k<1500, 47><<<(8 * 1500 * 47 + 255) / 256, 256, 0, stream>>>(obj_adj, maskO);

    colsum_part_k<<<dim3((NV + 255) / 256, CCH, B), 256, 0, stream>>>(A_OV, s1p, B, NO, NV);
    colsum_fin_k<<<dim3((B * NV + 255) / 256), 256, 0, stream>>>(s1p, rs1, B, NV);
    rowsum_inv_k<<<dim3((B * NO + 3) / 4), 256, 0, stream>>>(A_OV, rs1, rs2, B, NO, NV);

    // geometry (IT=64, JT=32):
    const int tilesV = 8, tilesO = 24;               // ceil(N/64)
    const int SVO = 8, SOV = 4;
    const int tpsVO = 6;   // ceil(ceil(1500/32)/8)
    const int tpsOV = 4;   // ceil(ceil(500/32)/4)
    const int G_AGG_V = B * tilesV;                  // 64  (full-row blocks)
    const int G_AGG_O = B * tilesO;                  // 192
    const int G_CR_VO = B * tilesV * SVO;            // 512
    const int G_CR_OV = B * tilesO * SOV;            // 768
    const int G_MLP_V = B * NV / 8;                  // 500
    const int G_MLP_O = B * NO / 8;                  // 1500
    const int G_XP_V = B * NV / 4;                   // 1000
    const int G_XP_O = B * NO / 4;                   // 3000
    const int G_GMF_V = B * tilesJV;                 // 128
    const int G_GMF_O = B * tilesJO;                 // 376

    // shared per-layer tail (everything after h/scores are computed)
    auto tail = [&](float* visout, float* objout) {
        sbmax2_k<<<16, 256, 0, stream>>>(sbV, smV, sbO, smO, NV, NO);
        AggP av{maskV, saV, sbV, smV, hTv, v1, NV, tilesV, tilesJV};
        AggP ao{maskO, saO, sbO, smO, hTo, o1, NO, tilesO, tilesJO};
        agg2_k<<<G_AGG_V + G_AGG_O, THR, 0, stream>>>(av, ao, G_AGG_V);
        CrossP cvo{A_OV, o1, nullptr, ppV, NV, NO, tilesV, tpsVO};
        CrossP cov{A_OV, v1, rs1, ppO, NO, NV, tilesO, tpsOV};
        cross2_k<<<G_CR_VO + G_CR_OV, THR, 0, stream>>>(cvo, cov, G_CR_VO);
        MlpP mv{ppV, rs1, SVO, o2g_W1, o2g_b1, o2g_W2, o2g_b2, v1, visout, B * NV};
        MlpP mo{ppO, rs2, SOV, g2o_W1, g2o_b1, g2o_W2, g2o_b2, o1, objout, B * NO};
        mlp2_k<<<G_MLP_V + G_MLP_O, 128, 0, stream>>>(mv, mo, G_MLP_V);
    };

    // ---- layer 1 (Kv=512, Ko=32) ----
    {
        XprepP xv{vis_memory, XbfV, wav1a, wav1b, saV, sbV, B * NV};
        XprepP xo{obj_memory, XbfO, wao1a, wao1b, saO, sbO, B * NO};
        xprep2_k<512, 32><<<G_XP_V + G_XP_O, 256, 0, stream>>>(xv, xo, G_XP_V);
        GmfP gv{XbfV, WTv1, hTv, NV, tilesJV};
        GmfP go{XbfO, WTo1, hTo, NO, tilesJO};
        gmf2_k<512, 32><<<G_GMF_V + G_GMF_O, 256, 0, stream>>>(gv, go, G_GMF_V);
        tail(visb, objb);
    }
    // ---- layer 2 (Kv=Ko=128) ----
    {
        XprepP xv{visb, XbfV, wav2a, wav2b, saV, sbV, B * NV};
        XprepP xo{objb, XbfO, wao2a, wao2b, saO, sbO, B * NO};
        xprep2_k<128, 128><<<G_XP_V + G_XP_O, 256, 0, stream>>>(xv, xo, G_XP_V);
        GmfP gv{XbfV, WTv2, hTv, NV, tilesJV};
        GmfP go{XbfO, WTo2, hTo, NO, tilesJO};
        gmf2_k<128, 128><<<G_GMF_V + G_GMF_O, 256, 0, stream>>>(gv, go, G_GMF_V);
        tail(visb, objb);
    }

    // output projections
    float* vis_out = (float*)d_out;
    float* obj_out = vis_out + (size_t)B * NV * DV;
    linear_k<0, 1, 0><<<dim3((B * NV + 3) / 4, (DV + 255) / 256), 128, 0, stream>>>(
        visb, img_W, img_b, nullptr, vis_out, B * NV, HD, DV);
    linear_k<0, 1, 0><<<dim3((B * NO + 3) / 4, 1), 128, 0, stream>>>(
        objb, obj_W, obj_b, nullptr, obj_out, B * NO, HD, DO);
}

// Round 5
// 589.033 us; speedup vs baseline: 1.0770x; 1.0770x over previous
//
#include <hip/hip_runtime.h>
#include <math.h>

#define EPSV 1e-5f
#define HD 128
#define IT 64
#define JT 32
#define WP 68
#define CCH 16
#define THR 256

typedef __attribute__((address_space(3))) uint32_t lds_u32_t;
typedef __attribute__((address_space(1))) uint32_t gbl_u32_t;
typedef __attribute__((ext_vector_type(8))) short bf16x8;
typedef __attribute__((ext_vector_type(4))) float f32x4;

__device__ __forceinline__ void async_copy16(const float* g, float* l) {
    __builtin_amdgcn_global_load_lds((const gbl_u32_t*)g, (lds_u32_t*)l, 16, 0, 0);
}

// stage a JT x HD fp32 tile (16 KB) global -> LDS via async DMA (256 threads)
__device__ __forceinline__ void stage_tile_async(const float* gsrc, float* lds, int t) {
    int wv = t >> 6, lane = t & 63;
#pragma unroll
    for (int it = 0; it < 4; ++it) {
        int c = it * 4 + wv;
        async_copy16(gsrc + c * 256 + lane * 4, lds + c * 256);
    }
}

// stage an 8 KB bf16 tile global -> LDS via async DMA (128 threads, 4 insts each)
__device__ __forceinline__ void stage_8k_128(const void* g, void* l, int t) {
    const float* gf = (const float*)g; float* lf = (float*)l;
    async_copy16(gf + t * 4, lf + t * 4);
    async_copy16(gf + t * 4 + 512, lf + t * 4 + 512);
    async_copy16(gf + t * 4 + 1024, lf + t * 4 + 1024);
    async_copy16(gf + t * 4 + 1536, lf + t * 4 + 1536);
}

__device__ __forceinline__ unsigned int f2bf(float f) {
    return __builtin_bit_cast(unsigned int, f) >> 16;
}

// round-to-nearest-even fp32 -> bf16
__device__ __forceinline__ unsigned short rne_bf16(float f) {
    unsigned int u = __builtin_bit_cast(unsigned int, f);
    u += 0x7FFFu + ((u >> 16) & 1u);
    return (unsigned short)(u >> 16);
}

// ---------------- param structs ----------------
struct WprepP { const float *W, *a1, *a2; unsigned short* WT; float *wa1, *wa2; int K; };
struct XprepP { const float* X; unsigned short* Xbf; const float *wa1, *wa2;
                float *sa, *sb; int rows; };
struct GmfP   { const unsigned short *Xbf, *WT; unsigned short* hT; int N, tilesJ; };
struct AggP  { const unsigned int* mask; const float *sa, *sb, *sm; const unsigned short* hT;
               float* out; int N, tiles, tilesJ; };
struct CrossP{ const float *A, *src, *rs1; float *pp; int iN, jN, tiles, tps; };
struct MlpP  { const float *pp, *scale; int S; const float *W1, *b1, *W2, *b2, *res;
               float *out; int rows; };

// ---------------- normalization scale kernels ----------------

__global__ void colsum_part_k(const float* __restrict__ A, float* __restrict__ s1p,
                              int B, int NO, int NV) {
    int v = blockIdx.x * 256 + threadIdx.x;
    int c = blockIdx.y, b = blockIdx.z;
    if (v >= NV) return;
    int chunk = (NO + CCH - 1) / CCH;
    int o0 = c * chunk;
    int o1 = o0 + chunk; if (o1 > NO) o1 = NO;
    const float* Ab = A + (size_t)b * NO * NV + v;
    float s = 0.f;
    for (int o = o0; o < o1; ++o) s += Ab[(size_t)o * NV];
    s1p[((size_t)b * CCH + c) * NV + v] = s;
}

__global__ void colsum_fin_k(const float* __restrict__ s1p, float* __restrict__ rs1,
                             int B, int NV) {
    int idx = blockIdx.x * 256 + threadIdx.x;
    if (idx >= B * NV) return;
    int b = idx / NV, v = idx - b * NV;
    float s = 0.f;
    for (int c = 0; c < CCH; ++c) s += s1p[((size_t)b * CCH + c) * NV + v];
    rs1[idx] = 1.f / (s + EPSV);
}

__global__ void rowsum_inv_k(const float* __restrict__ A, const float* __restrict__ rs1,
                             float* __restrict__ rs2, int B, int NO, int NV) {
    int row = blockIdx.x * (blockDim.x >> 6) + (threadIdx.x >> 6);
    int lane = threadIdx.x & 63;
    if (row >= B * NO) return;
    int b = row / NO;
    const float* Ar = A + (size_t)row * NV;
    const float* r1 = rs1 + (size_t)b * NV;
    float s = 0.f;
    for (int v = lane; v < NV; v += 64) s += Ar[v] * r1[v];
    for (int off = 32; off; off >>= 1) s += __shfl_xor(s, off, 64);
    if (lane == 0) rs2[row] = 1.f / (s + EPSV);
}

// ---------------- adjacency bitmask generation (runs once, both layers reuse) ----
// maskT layout: [b][word][i] u32, bit(j&31) = adj[b][i][word*32+j&31] > 0.
// One thread builds one word from 8 coalesced float4 loads (128 B/thread).
template<int N, int TILESJ>
__global__ __launch_bounds__(256)
void maskg_k(const float* __restrict__ adj, unsigned int* __restrict__ maskT) {
    int tid = blockIdx.x * 256 + threadIdx.x;
    int w = tid % TILESJ;
    int rowid = tid / TILESJ;                        // b*N + i
    if (rowid >= 8 * N) return;
    int b = rowid / N, i = rowid - b * N;
    int j0 = w * 32;
    const float* src = adj + (size_t)rowid * N + j0;
    unsigned int bits = 0u;
    if (j0 + 32 <= N) {
#pragma unroll
        for (int q = 0; q < 8; ++q) {
            float4 v = ((const float4*)src)[q];
            bits |= (v.x > 0.f ? 1u : 0u) << (q * 4 + 0);
            bits |= (v.y > 0.f ? 1u : 0u) << (q * 4 + 1);
            bits |= (v.z > 0.f ? 1u : 0u) << (q * 4 + 2);
            bits |= (v.w > 0.f ? 1u : 0u) << (q * 4 + 3);
        }
    } else {
#pragma unroll
        for (int r = 0; r < 32; ++r)
            if (j0 + r < N) bits |= (src[r] > 0.f ? 1u : 0u) << r;
    }
    maskT[((size_t)b * TILESJ + w) * N + i] = bits;
}

// ---------------- weight prep (runs once): WT[c][k] bf16 + wa1/wa2 = W @ a ----------
__global__ __launch_bounds__(256)
void wprep_k(WprepP p0, WprepP p1, WprepP p2, WprepP p3, int e0, int e1, int e2) {
    __shared__ float lw[32][129];
    __shared__ float a1s[128], a2s[128];
    int bid = blockIdx.x;
    const WprepP& P = bid < e0 ? p0 : bid < e1 ? p1 : bid < e2 ? p2 : p3;
    int lb = bid < e0 ? bid : bid < e1 ? bid - e0 : bid < e2 ? bid - e1 : bid - e2;
    int k0 = lb * 32, K = P.K;
    int t = threadIdx.x;
    if (t < 128) { a1s[t] = P.a1[t]; a2s[t] = P.a2[t]; }
    for (int idx = t; idx < 32 * 32; idx += 256) {   // float4 granularity
        int kk = idx >> 5, c4 = idx & 31;
        float4 v = ((const float4*)(P.W + (size_t)(k0 + kk) * 128))[c4];
        lw[kk][c4 * 4 + 0] = v.x; lw[kk][c4 * 4 + 1] = v.y;
        lw[kk][c4 * 4 + 2] = v.z; lw[kk][c4 * 4 + 3] = v.w;
    }
    __syncthreads();
    // wa1/wa2: 8 lanes per k-row
    int kk = t >> 3, g = t & 7;
    float s1 = 0.f, s2 = 0.f;
    for (int c = g; c < 128; c += 8) {
        float w = lw[kk][c];
        s1 = fmaf(w, a1s[c], s1);
        s2 = fmaf(w, a2s[c], s2);
    }
    s1 += __shfl_xor(s1, 1, 64); s1 += __shfl_xor(s1, 2, 64); s1 += __shfl_xor(s1, 4, 64);
    s2 += __shfl_xor(s2, 1, 64); s2 += __shfl_xor(s2, 2, 64); s2 += __shfl_xor(s2, 4, 64);
    if (g == 0) { P.wa1[k0 + kk] = s1; P.wa2[k0 + kk] = s2; }
    // transposed bf16 store: WT[c][k]
    for (int idx = t; idx < 4096; idx += 256) {
        int c = idx >> 5, k = idx & 31;
        P.WT[(size_t)c * K + k0 + k] = rne_bf16(lw[k][c]);
    }
}

// ---------------- X prep: Xbf = rne_bf16(X); sa = X.wa1, sb = X.wa2 (exact fp32) ----
template<int K>
__device__ void xprep_body(const XprepP& P, int lb) {
    int t = threadIdx.x, wv = t >> 6, lane = t & 63;
    int row = lb * 4 + wv;
    if (row >= P.rows) return;
    const float4* x4 = (const float4*)(P.X + (size_t)row * K);
    const float4* w14 = (const float4*)P.wa1;
    const float4* w24 = (const float4*)P.wa2;
    unsigned short* xb = P.Xbf + (size_t)row * K;
    float s1 = 0.f, s2 = 0.f;
    constexpr int K4 = K / 4;
    constexpr int NI = (K4 + 63) / 64;
#pragma unroll
    for (int i = 0; i < NI; ++i) {
        int k4 = i * 64 + lane;
        if ((K4 % 64 == 0) || (k4 < K4)) {
            float4 x = x4[k4];
            float4 a = w14[k4];
            float4 b = w24[k4];
            s1 += x.x * a.x + x.y * a.y + x.z * a.z + x.w * a.w;
            s2 += x.x * b.x + x.y * b.y + x.z * b.z + x.w * b.w;
            ushort4 p = make_ushort4(rne_bf16(x.x), rne_bf16(x.y),
                                     rne_bf16(x.z), rne_bf16(x.w));
            *(ushort4*)(xb + (size_t)k4 * 4) = p;
        }
    }
#pragma unroll
    for (int off = 32; off; off >>= 1) {
        s1 += __shfl_xor(s1, off, 64);
        s2 += __shfl_xor(s2, off, 64);
    }
    if (lane == 0) { P.sa[row] = s1; P.sb[row] = s2; }
}

template<int KV, int KO>
__global__ __launch_bounds__(256)
void xprep2_k(XprepP V, XprepP O, int GV) {
    int bid = blockIdx.x;
    if (bid < GV) xprep_body<KV>(V, bid);
    else          xprep_body<KO>(O, bid - GV);
}

// ---------------- MFMA h-GEMM producing hT directly (bank-swizzled layout) --------
// D[m=c][n=jl] = sum_k WT[c][k] * Xbf[row0+jl][k]  via mfma_f32_16x16x32_bf16.
// hT tile layout is SWIZZLED: element (c, jl) lives at ushort index
//   c*32 + (jl ^ (((c>>1)&3)<<3))
// so agg's per-quad ds_read_b128 of the 64-B-stride row tile is bank-conflict-free
// while the global_load_lds DMA stays linear (swizzle baked into global layout).
template<int K>
__device__ void gmf_body(const GmfP& P, int lb) {
    int tilesJ = P.tilesJ, N = P.N;
    int b = lb / tilesJ, jt = lb - b * tilesJ;
    int t = threadIdx.x, wv = t >> 6, lane = t & 63;
    int ml = lane & 15, quad = lane >> 4;
    const unsigned short* xb = P.Xbf + ((size_t)b * N + (size_t)jt * 32) * K;
    const unsigned short* wt0 = P.WT + (size_t)(wv * 32 + ml) * K;
    const unsigned short* wt1 = wt0 + (size_t)16 * K;
    const unsigned short* xb0 = xb + (size_t)ml * K;
    const unsigned short* xb1 = xb + (size_t)(16 + ml) * K;
    f32x4 acc00 = {0.f, 0.f, 0.f, 0.f}, acc01 = acc00, acc10 = acc00, acc11 = acc00;
#pragma unroll 4
    for (int kt = 0; kt < K / 32; ++kt) {
        int kk = kt * 32 + quad * 8;
        bf16x8 a0 = *(const bf16x8*)(wt0 + kk);
        bf16x8 a1 = *(const bf16x8*)(wt1 + kk);
        bf16x8 b0 = *(const bf16x8*)(xb0 + kk);
        bf16x8 b1 = *(const bf16x8*)(xb1 + kk);
        acc00 = __builtin_amdgcn_mfma_f32_16x16x32_bf16(a0, b0, acc00, 0, 0, 0);
        acc01 = __builtin_amdgcn_mfma_f32_16x16x32_bf16(a0, b1, acc01, 0, 0, 0);
        acc10 = __builtin_amdgcn_mfma_f32_16x16x32_bf16(a1, b0, acc10, 0, 0, 0);
        acc11 = __builtin_amdgcn_mfma_f32_16x16x32_bf16(a1, b1, acc11, 0, 0, 0);
    }
    unsigned short* hb = P.hT + (size_t)(b * tilesJ + jt) * 4096;
    int nvalid = N - jt * 32; if (nvalid > 32) nvalid = 32;
    bool ok0 = ml < nvalid, ok1 = (16 + ml) < nvalid;
    int c0 = wv * 32 + quad * 4;
#pragma unroll
    for (int r = 0; r < 4; ++r) {
        int ca = c0 + r, cb = c0 + 16 + r;
        int swa = ((ca >> 1) & 3) << 3, swb = ((cb >> 1) & 3) << 3;
        hb[ca * 32 + (ml ^ swa)]        = ok0 ? rne_bf16(acc00[r]) : 0;
        hb[ca * 32 + ((16 + ml) ^ swa)] = ok1 ? rne_bf16(acc01[r]) : 0;
        hb[cb * 32 + (ml ^ swb)]        = ok0 ? rne_bf16(acc10[r]) : 0;
        hb[cb * 32 + ((16 + ml) ^ swb)] = ok1 ? rne_bf16(acc11[r]) : 0;
    }
}

template<int KV, int KO>
__global__ __launch_bounds__(256)
void gmf2_k(GmfP V, GmfP O, int GV) {
    int bid = blockIdx.x;
    if (bid < GV) gmf_body<KV>(V, bid);
    else          gmf_body<KO>(O, bid - GV);
}

// ---------------- fused per-batch sb max ----------------
__global__ __launch_bounds__(256)
void sbmax2_k(const float* __restrict__ sbV, float* __restrict__ smV,
              const float* __restrict__ sbO, float* __restrict__ smO,
              int NV, int NO) {
    __shared__ float red[256];
    int b0 = blockIdx.x, t = threadIdx.x;
    const float* sb; float* out; int N;
    if (b0 < 8) { sb = sbV + (size_t)b0 * NV; out = smV + b0; N = NV; }
    else        { sb = sbO + (size_t)(b0 - 8) * NO; out = smO + (b0 - 8); N = NO; }
    float m = -INFINITY;
    for (int j = t; j < N; j += 256) m = fmaxf(m, sb[j]);
    red[t] = m; __syncthreads();
    for (int s = 128; s; s >>= 1) {
        if (t < s) red[t] = fmaxf(red[t], red[t + s]);
        __syncthreads();
    }
    if (t == 0) *out = red[0];
}

// ---------------- MFMA GAT aggregation, FULL-ROW, 32-row blocks ----------------
// 128 threads (2 waves), each block owns 32 output rows and walks ALL tilesJ
// j-tiles. Each lane computes ITS OWN A-fragment w's directly (A[m=lane&15]
// [k=quad*8+i], j=k — no LDS redistribution, no producer barrier). hT DMA is
// depth-4 over 5 LDS buffers with counted vmcnt (4 loads/stage × 3 in flight
// = vmcnt(12)). z complete in-block -> /z, relu, final store (no fin pass).
struct SharedAgg32 {
    unsigned short hsT[5][128][32];    // [c][jl-swz] bf16, DMA'd from hT (5-deep)
    unsigned int mask_s[48][32];       // [tile][row] adjacency bits
    float sb_s[48 * 32];               // sb for the whole j-range
    float z_s[32];
};

__device__ void agg_body(SharedAgg32& sm, const AggP& P, int lbid) {
    int tiles = P.tiles;                             // ceil(N/32)
    int b = lbid / tiles;
    int i0 = (lbid - b * tiles) * 32;
    int N = P.N, T = P.tilesJ;
    int t = threadIdx.x;
    int wv = t >> 6, lane = t & 63, quad = lane >> 4, ml = lane & 15;
    // stage mask (uint4) + sb (float4); OOB reads land in adjacent ws (benign:
    // garbage only reaches rows/cols >= N, which are masked or not stored)
    const unsigned int* mb = P.mask + (size_t)b * T * N + i0;
    for (int idx = t; idx < T * 8; idx += 128) {
        int w = idx >> 3, r4 = idx & 7;
        *(uint4*)&sm.mask_s[w][r4 * 4] = *(const uint4*)&mb[(size_t)w * N + r4 * 4];
    }
    const float* sbb = P.sb + (size_t)b * N;
    for (int idx = t; idx < T * 8; idx += 128)
        ((float4*)sm.sb_s)[idx] = ((const float4*)sbb)[idx];
    // per-lane row state (reg-resident)
    int row_loc = wv * 16 + ml;
    int irow = i0 + row_loc;
    float sa = (irow < N) ? P.sa[(size_t)b * N + irow] : 0.f;
    float e0 = sa + P.sm[b];
    float m = e0 > 0.f ? e0 : 0.2f * e0;
    __syncthreads();                                 // mask_s/sb_s visible
    // prologue: DMA tiles 0..3 (depth-4)
    const unsigned short* hTb = P.hT + (size_t)b * T * 4096;
    stage_8k_128(hTb, &sm.hsT[0][0][0], t);
    if (T > 1) stage_8k_128(hTb + 4096, &sm.hsT[1][0][0], t);
    if (T > 2) stage_8k_128(hTb + 8192, &sm.hsT[2][0][0], t);
    if (T > 3) stage_8k_128(hTb + 12288, &sm.hsT[3][0][0], t);

    int nq2 = (quad ^ ((ml >> 1) & 3)) * 8;          // B-frag granule (swizzle fold)
    f32x4 acc[8];
#pragma unroll
    for (int nt = 0; nt < 8; ++nt)
#pragma unroll
        for (int r = 0; r < 4; ++r) acc[nt][r] = 0.f;
    float zacc = 0.f;
    for (int tt = 0; tt < T; ++tt) {
        int cur = tt - (tt / 5) * 5;                 // tt % 5
        unsigned int mq = sm.mask_s[tt][row_loc] >> (quad * 8);
        float4 s0 = *(const float4*)&sm.sb_s[tt * 32 + quad * 8];
        float4 s1 = *(const float4*)&sm.sb_s[tt * 32 + quad * 8 + 4];
        float sv[8] = {s0.x, s0.y, s0.z, s0.w, s1.x, s1.y, s1.z, s1.w};
        float w_[8];
#pragma unroll
        for (int i = 0; i < 8; ++i) {
            float e = sa + sv[i];
            e = e > 0.f ? e : 0.2f * e;
            float ww = __expf(e - m);
            ww = ((mq >> i) & 1u) ? ww : 0.f;
            zacc += ww;
            w_[i] = ww;
        }
        unsigned int u0 = f2bf(w_[0]) | (__builtin_bit_cast(unsigned int, w_[1]) & 0xFFFF0000u);
        unsigned int u1 = f2bf(w_[2]) | (__builtin_bit_cast(unsigned int, w_[3]) & 0xFFFF0000u);
        unsigned int u2 = f2bf(w_[4]) | (__builtin_bit_cast(unsigned int, w_[5]) & 0xFFFF0000u);
        unsigned int u3 = f2bf(w_[6]) | (__builtin_bit_cast(unsigned int, w_[7]) & 0xFFFF0000u);
        uint4 af = make_uint4(u0, u1, u2, u3);
        bf16x8 afrag = __builtin_bit_cast(bf16x8, af);
        // counted drain: keep up to 3 future stages (12 vm ops) in flight
        int rem = T - tt;
        if (rem >= 4)      asm volatile("s_waitcnt vmcnt(12)" ::: "memory");
        else if (rem == 3) asm volatile("s_waitcnt vmcnt(8)" ::: "memory");
        else if (rem == 2) asm volatile("s_waitcnt vmcnt(4)" ::: "memory");
        else               asm volatile("s_waitcnt vmcnt(0)" ::: "memory");
        __builtin_amdgcn_s_barrier();
        asm volatile("" ::: "memory");
        if (tt + 4 < T) {
            int nb = tt + 4; nb -= (nb / 5) * 5;
            stage_8k_128(hTb + (size_t)(tt + 4) * 4096, &sm.hsT[nb][0][0], t);
        }
#pragma unroll
        for (int nt = 0; nt < 8; ++nt) {
            bf16x8 bfrag = *(const bf16x8*)&sm.hsT[cur][nt * 16 + ml][nq2];
            acc[nt] = __builtin_amdgcn_mfma_f32_16x16x32_bf16(afrag, bfrag, acc[nt], 0, 0, 0);
        }
    }
    // z: reduce over 4 quads sharing a row
    zacc += __shfl_xor(zacc, 16, 64);
    zacc += __shfl_xor(zacc, 32, 64);
    if (quad == 0) sm.z_s[row_loc] = zacc;
    __syncthreads();
    // epilogue: /z, relu, FINAL store (C/D: col=lane&15, row=quad*4+r)
    float* outb = P.out + (size_t)b * N * HD;
#pragma unroll
    for (int r = 0; r < 4; ++r) {
        int rr = wv * 16 + quad * 4 + r;
        float inv = 1.f / sm.z_s[rr];
        int row = i0 + rr;
        if (row < N) {
#pragma unroll
            for (int nt = 0; nt < 8; ++nt)
                outb[(size_t)row * HD + nt * 16 + ml] = fmaxf(acc[nt][r] * inv, 0.f);
        }
    }
}

__global__ __launch_bounds__(128)
void agg2_k(AggP V, AggP O, int GVb) {
    __shared__ SharedAgg32 sm;
    int bid = blockIdx.x;
    if (bid < GVb) agg_body(sm, V, bid);
    else           agg_body(sm, O, bid - GVb);
}

// ---------------- 256-thread fp32 tile FMA (cross kernels) ----------------
__device__ __forceinline__ void tile_fma256(const float (*hs)[HD], const float (*ws)[WP],
                                            int rg, int c0, float acc[4][8]) {
#pragma unroll 8
    for (int jl = 0; jl < JT; ++jl) {
        float4 h0 = *(const float4*)&hs[jl][c0];
        float4 h1 = *(const float4*)&hs[jl][c0 + 64];
        float4 w4 = *(const float4*)&ws[jl][rg * 4];
        float wq[4] = {w4.x, w4.y, w4.z, w4.w};
#pragma unroll
        for (int q = 0; q < 4; ++q) {
            float w = wq[q];
            acc[q][0] = fmaf(w, h0.x, acc[q][0]);
            acc[q][1] = fmaf(w, h0.y, acc[q][1]);
            acc[q][2] = fmaf(w, h0.z, acc[q][2]);
            acc[q][3] = fmaf(w, h0.w, acc[q][3]);
            acc[q][4] = fmaf(w, h1.x, acc[q][4]);
            acc[q][5] = fmaf(w, h1.y, acc[q][5]);
            acc[q][6] = fmaf(w, h1.z, acc[q][6]);
            acc[q][7] = fmaf(w, h1.w, acc[q][7]);
        }
    }
}

__device__ __forceinline__ void part_store256(float* __restrict__ pp, size_t base,
                                              int i0, int N, int rg, int c0,
                                              float acc[4][8]) {
#pragma unroll
    for (int q = 0; q < 4; ++q) {
        int i = i0 + rg * 4 + q;
        if (i >= N) continue;
        float* op = pp + base + (size_t)i * HD;
        *(float4*)&op[c0]      = make_float4(acc[q][0], acc[q][1], acc[q][2], acc[q][3]);
        *(float4*)&op[c0 + 64] = make_float4(acc[q][4], acc[q][5], acc[q][6], acc[q][7]);
    }
}

struct SharedTile { float hs[2][JT][HD]; float ws[2][JT][WP]; };

// ---------------- fused cross (vo + ov), pipelined fp32 ----------------
__device__ void cross_vo_body(SharedTile& sm, const CrossP& P, int lbid) {
    int tiles = P.tiles;
    int split = lbid / (8 * tiles);
    int rem = lbid - split * 8 * tiles;
    int b = rem / tiles;
    int i0 = (rem - b * tiles) * IT;
    int NVl = P.iN, NOl = P.jN;
    int j_begin = split * P.tps * JT;
    if (j_begin >= NOl) return;
    int j_end = j_begin + P.tps * JT;
    if (j_end > NOl) j_end = NOl;
    int T = (j_end - j_begin + JT - 1) / JT;
    int t = threadIdx.x;
    int rg = t >> 4, c0 = (t & 15) * 4;
    int il = t & 63, jlb = t >> 6;
    float acc[4][8];
#pragma unroll
    for (int q = 0; q < 4; ++q)
#pragma unroll
        for (int x = 0; x < 8; ++x) acc[q][x] = 0.f;
    const float* Ab = P.A + (size_t)b * NOl * NVl;
    const float* srcb = P.src + (size_t)b * NOl * HD;
    int v = i0 + il;
    float w8[8];
    stage_tile_async(srcb + (size_t)j_begin * HD, &sm.hs[0][0][0], t);
#pragma unroll
    for (int k = 0; k < 8; ++k) {
        int o = j_begin + jlb + k * 4;
        w8[k] = (v < NVl && o < NOl) ? Ab[(size_t)o * NVl + v] : 0.f;
    }
    for (int tt = 0; tt < T; ++tt) {
        int cur = tt & 1;
#pragma unroll
        for (int k = 0; k < 8; ++k) sm.ws[cur][jlb + k * 4][il] = w8[k];
        __syncthreads();
        if (tt + 1 < T) {
            int jn = j_begin + (tt + 1) * JT;
            stage_tile_async(srcb + (size_t)jn * HD, &sm.hs[1 - cur][0][0], t);
#pragma unroll
            for (int k = 0; k < 8; ++k) {
                int o = jn + jlb + k * 4;
                w8[k] = (v < NVl && o < NOl) ? Ab[(size_t)o * NVl + v] : 0.f;
            }
        }
        tile_fma256(sm.hs[cur], sm.ws[cur], rg, c0, acc);
    }
    size_t rowsTot = (size_t)8 * NVl;
    part_store256(P.pp, ((size_t)split * rowsTot + (size_t)b * NVl) * HD, i0, NVl, rg, c0, acc);
}

__device__ void cross_ov_body(SharedTile& sm, const CrossP& P, int lbid) {
    int tiles = P.tiles;
    int split = lbid / (8 * tiles);
    int rem = lbid - split * 8 * tiles;
    int b = rem / tiles;
    int i0 = (rem - b * tiles) * IT;
    int NOl = P.iN, NVl = P.jN;
    int j_begin = split * P.tps * JT;
    if (j_begin >= NVl) return;
    int j_end = j_begin + P.tps * JT;
    if (j_end > NVl) j_end = NVl;
    int T = (j_end - j_begin + JT - 1) / JT;
    int t = threadIdx.x;
    int rg = t >> 4, c0 = (t & 15) * 4;
    int il = t >> 2, j4 = (t & 3) * 4;
    float acc[4][8];
#pragma unroll
    for (int q = 0; q < 4; ++q)
#pragma unroll
        for (int x = 0; x < 8; ++x) acc[q][x] = 0.f;
    const float* Ab = P.A + (size_t)b * NOl * NVl;
    const float* srcb = P.src + (size_t)b * NVl * HD;
    const float* r1b = P.rs1 + (size_t)b * NVl;
    int orow = i0 + il;
    float4 a4[2], r4[2];
    stage_tile_async(srcb + (size_t)j_begin * HD, &sm.hs[0][0][0], t);
#pragma unroll
    for (int k = 0; k < 2; ++k) {
        int vv = j_begin + j4 + k * 16;
        float4 av = make_float4(0.f,0.f,0.f,0.f), rv = make_float4(0.f,0.f,0.f,0.f);
        if (orow < NOl) {
            if (vv + 3 < NVl) {
                av = *(const float4*)&Ab[(size_t)orow * NVl + vv];
                rv = *(const float4*)&r1b[vv];
            } else {
                float* ap = (float*)&av; float* rp = (float*)&rv;
                for (int r = 0; r < 4; ++r)
                    if (vv + r < NVl) { ap[r] = Ab[(size_t)orow * NVl + vv + r]; rp[r] = r1b[vv + r]; }
            }
        }
        a4[k] = av; r4[k] = rv;
    }
    for (int tt = 0; tt < T; ++tt) {
        int cur = tt & 1;
#pragma unroll
        for (int k = 0; k < 2; ++k) {
            float wv[4] = {a4[k].x * r4[k].x, a4[k].y * r4[k].y,
                           a4[k].z * r4[k].z, a4[k].w * r4[k].w};
#pragma unroll
            for (int r = 0; r < 4; ++r) sm.ws[cur][j4 + r + k * 16][il] = wv[r];
        }
        __syncthreads();
        if (tt + 1 < T) {
            int jn = j_begin + (tt + 1) * JT;
            stage_tile_async(srcb + (size_t)jn * HD, &sm.hs[1 - cur][0][0], t);
#pragma unroll
            for (int k = 0; k < 2; ++k) {
                int vv = jn + j4 + k * 16;
                float4 av = make_float4(0.f,0.f,0.f,0.f), rv = make_float4(0.f,0.f,0.f,0.f);
                if (orow < NOl) {
                    if (vv + 3 < NVl) {
                        av = *(const float4*)&Ab[(size_t)orow * NVl + vv];
                        rv = *(const float4*)&r1b[vv];
                    } else {
                        float* ap = (float*)&av; float* rp = (float*)&rv;
                        for (int r = 0; r < 4; ++r)
                            if (vv + r < NVl) { ap[r] = Ab[(size_t)orow * NVl + vv + r]; rp[r] = r1b[vv + r]; }
                    }
                }
                a4[k] = av; r4[k] = rv;
            }
        }
        tile_fma256(sm.hs[cur], sm.ws[cur], rg, c0, acc);
    }
    size_t rowsTot = (size_t)8 * NOl;
    part_store256(P.pp, ((size_t)split * rowsTot + (size_t)b * NOl) * HD, i0, NOl, rg, c0, acc);
}

__global__ __launch_bounds__(256)
void cross2_k(CrossP VO, CrossP OV, int GVOb) {
    __shared__ SharedTile sm;
    int bid = blockIdx.x;
    if (bid < GVOb) cross_vo_body(sm, VO, bid);
    else            cross_ov_body(sm, OV, bid - GVOb);
}

// ---------------- fused MLP: out = (relu(x@W1+b1))@W2 + b2 + res ----------------
__global__ __launch_bounds__(128)
void mlp2_k(MlpP V, MlpP O, int GVb) {
    __shared__ float xs[8][HD];
    __shared__ float hh[8][HD];
    int bid = blockIdx.x;
    const MlpP& P = (bid < GVb) ? V : O;
    int row0 = ((bid < GVb) ? bid : bid - GVb) * 8;
    int rows = P.rows;
    int t = threadIdx.x;
    for (int l = t; l < 8 * 32; l += 128) {
        int r = l >> 5, c4 = l & 31;
        int row = row0 + r;
        float4 v = make_float4(0.f, 0.f, 0.f, 0.f);
        if (row < rows) {
            for (int s = 0; s < P.S; ++s) {
                float4 p = ((const float4*)P.pp)[((size_t)s * rows + row) * 32 + c4];
                v.x += p.x; v.y += p.y; v.z += p.z; v.w += p.w;
            }
            float sc = P.scale[row];
            v.x *= sc; v.y *= sc; v.z *= sc; v.w *= sc;
        }
        ((float4*)&xs[r][0])[c4] = v;
    }
    __syncthreads();
    int wv = t >> 6, tt = t & 63, rb = wv * 4;
    float a0[4] = {0.f, 0.f, 0.f, 0.f}, a1v[4] = {0.f, 0.f, 0.f, 0.f};
#pragma unroll 4
    for (int k = 0; k < HD; ++k) {
        float w0 = P.W1[(size_t)k * HD + tt];
        float w1 = P.W1[(size_t)k * HD + tt + 64];
#pragma unroll
        for (int r = 0; r < 4; ++r) {
            float x = xs[rb + r][k];
            a0[r] = fmaf(x, w0, a0[r]);
            a1v[r] = fmaf(x, w1, a1v[r]);
        }
    }
    float bb0 = P.b1[tt], bb1 = P.b1[tt + 64];
#pragma unroll
    for (int r = 0; r < 4; ++r) {
        hh[rb + r][tt]      = fmaxf(a0[r] + bb0, 0.f);
        hh[rb + r][tt + 64] = fmaxf(a1v[r] + bb1, 0.f);
    }
    __syncthreads();
    float c0a[4] = {0.f, 0.f, 0.f, 0.f}, c1a[4] = {0.f, 0.f, 0.f, 0.f};
#pragma unroll 4
    for (int k = 0; k < HD; ++k) {
        float w0 = P.W2[(size_t)k * HD + tt];
        float w1 = P.W2[(size_t)k * HD + tt + 64];
#pragma unroll
        for (int r = 0; r < 4; ++r) {
            float x = hh[rb + r][k];
            c0a[r] = fmaf(x, w0, c0a[r]);
            c1a[r] = fmaf(x, w1, c1a[r]);
        }
    }
    float d0 = P.b2[tt], d1 = P.b2[tt + 64];
#pragma unroll
    for (int r = 0; r < 4; ++r) {
        int row = row0 + rb + r;
        if (row >= rows) continue;
        P.out[(size_t)row * HD + tt]      = c0a[r] + d0 + P.res[(size_t)row * HD + tt];
        P.out[(size_t)row * HD + tt + 64] = c1a[r] + d1 + P.res[(size_t)row * HD + tt + 64];
    }
}

// ---------------- output projection ----------------
template<int RELU, int BIAS, int RES>
__global__ __launch_bounds__(128)
void linear_k(const float* __restrict__ X, const float* __restrict__ W,
              const float* __restrict__ bias, const float* __restrict__ res,
              float* __restrict__ out, int rows, int K, int Dout) {
    __shared__ float xs[4][512];
    int row0 = blockIdx.x * 4;
    int t = threadIdx.x;
    int K4 = K >> 2;
    for (int l = t; l < 4 * K4; l += 128) {
        int r = l / K4, c4 = l - r * K4;
        float4 val = make_float4(0.f, 0.f, 0.f, 0.f);
        if (row0 + r < rows) val = ((const float4*)(X + (size_t)(row0 + r) * K))[c4];
        ((float4*)&xs[r][0])[c4] = val;
    }
    __syncthreads();
    int chunk = Dout < 256 ? Dout : 256;
    int half = chunk >> 1;
    if (t >= half) return;
    int c0 = blockIdx.y * chunk + t;
    int c1 = c0 + half;
    float a00 = 0, a01 = 0, a02 = 0, a03 = 0, a10 = 0, a11 = 0, a12 = 0, a13 = 0;
#pragma unroll 4
    for (int k = 0; k < K; ++k) {
        float w0 = W[(size_t)k * Dout + c0];
        float w1 = W[(size_t)k * Dout + c1];
        float x0 = xs[0][k], x1 = xs[1][k], x2 = xs[2][k], x3 = xs[3][k];
        a00 = fmaf(x0, w0, a00); a01 = fmaf(x1, w0, a01);
        a02 = fmaf(x2, w0, a02); a03 = fmaf(x3, w0, a03);
        a10 = fmaf(x0, w1, a10); a11 = fmaf(x1, w1, a11);
        a12 = fmaf(x2, w1, a12); a13 = fmaf(x3, w1, a13);
    }
    float accs[2][4] = {{a00, a01, a02, a03}, {a10, a11, a12, a13}};
    int cs[2] = {c0, c1};
    for (int h = 0; h < 2; ++h) {
        float bv = BIAS ? bias[cs[h]] : 0.f;
        for (int r = 0; r < 4; ++r) {
            int row = row0 + r;
            if (row >= rows) continue;
            float v = accs[h][r] + bv;
            if (RES) v += res[(size_t)row * Dout + cs[h]];
            if (RELU) v = fmaxf(v, 0.f);
            out[(size_t)row * Dout + cs[h]] = v;
        }
    }
}

// ---------------- host launcher ----------------
extern "C" void kernel_launch(void* const* d_in, const int* in_sizes, int n_in,
                              void* d_out, int out_size, void* d_ws, size_t ws_size,
                              hipStream_t stream) {
    const int B = 8, NV = 500, NO = 1500, DV = 512, DO = 32;
    const float* vis_memory = (const float*)d_in[0];
    const float* obj_memory = (const float*)d_in[1];
    const float* vis_adj    = (const float*)d_in[2];
    const float* obj_adj    = (const float*)d_in[3];
    const float* A_OV       = (const float*)d_in[4];
    const float* Wv1  = (const float*)d_in[5];
    const float* av1a = (const float*)d_in[6];
    const float* av1b = (const float*)d_in[7];
    const float* Wv2  = (const float*)d_in[8];
    const float* av2a = (const float*)d_in[9];
    const float* av2b = (const float*)d_in[10];
    const float* Wo1  = (const float*)d_in[11];
    const float* ao1a = (const float*)d_in[12];
    const float* ao1b = (const float*)d_in[13];
    const float* Wo2  = (const float*)d_in[14];
    const float* ao2a = (const float*)d_in[15];
    const float* ao2b = (const float*)d_in[16];
    const float* g2o_W1 = (const float*)d_in[17];
    const float* g2o_b1 = (const float*)d_in[18];
    const float* g2o_W2 = (const float*)d_in[19];
    const float* g2o_b2 = (const float*)d_in[20];
    const float* o2g_W1 = (const float*)d_in[21];
    const float* o2g_b1 = (const float*)d_in[22];
    const float* o2g_W2 = (const float*)d_in[23];
    const float* o2g_b2 = (const float*)d_in[24];
    const float* img_W = (const float*)d_in[25];
    const float* img_b = (const float*)d_in[26];
    const float* obj_W = (const float*)d_in[27];
    const float* obj_b = (const float*)d_in[28];

    const int tilesJV = 16, tilesJO = 47;            // ceil(N/32)

    float* wsp = (float*)d_ws;
    size_t off = 0;
    auto alloc = [&](size_t n) { float* p = wsp + off; off += (n + 3) & ~(size_t)3; return p; };
    float* rs1   = alloc(B * NV);
    float* rs2   = alloc(B * NO);
    float* saV   = alloc(B * NV);
    float* sbV   = alloc(B * NV);
    float* smV   = alloc(B);
    float* saO   = alloc(B * NO);
    float* sbO   = alloc(B * NO);
    float* smO   = alloc(B);
    float* s1p   = alloc((size_t)B * CCH * NV);
    // adjacency bitmasks (transposed [b][word][i], u32)
    unsigned int* maskV = (unsigned int*)alloc((size_t)B * tilesJV * NV);
    unsigned int* maskO = (unsigned int*)alloc((size_t)B * tilesJO * NO);
    // weight-prep outputs (bf16 transposed W + score vectors)
    unsigned short* WTv1 = (unsigned short*)alloc(128 * 512 / 2);
    unsigned short* WTo1 = (unsigned short*)alloc(128 * 32 / 2);
    unsigned short* WTv2 = (unsigned short*)alloc(128 * 128 / 2);
    unsigned short* WTo2 = (unsigned short*)alloc(128 * 128 / 2);
    float* wav1a = alloc(512); float* wav1b = alloc(512);
    float* wao1a = alloc(32);  float* wao1b = alloc(32);
    float* wav2a = alloc(128); float* wav2b = alloc(128);
    float* wao2a = alloc(128); float* wao2b = alloc(128);
    // bf16 X buffers (max over layers: vis 4000x512, obj 12000x128)
    unsigned short* XbfV = (unsigned short*)alloc((size_t)B * NV * 512 / 2);
    unsigned short* XbfO = (unsigned short*)alloc((size_t)B * NO * 128 / 2);
    unsigned short* hTv = (unsigned short*)alloc((size_t)B * tilesJV * 4096 / 2);
    unsigned short* hTo = (unsigned short*)alloc((size_t)B * tilesJO * 4096 / 2);
    float* v1    = alloc((size_t)B * NV * HD);
    float* o1    = alloc((size_t)B * NO * HD);
    float* visb  = alloc((size_t)B * NV * HD);
    float* objb  = alloc((size_t)B * NO * HD);
    float* ppV   = alloc((size_t)8 * B * NV * HD);
    float* ppO   = alloc((size_t)4 * B * NO * HD);
    alloc(16384);                                    // tail pad for async/OOB reads

    // weight prep (once): 16 + 1 + 4 + 4 = 25 blocks
    {
        WprepP w0{Wv1, av1a, av1b, WTv1, wav1a, wav1b, DV};
        WprepP w1{Wo1, ao1a, ao1b, WTo1, wao1a, wao1b, DO};
        WprepP w2{Wv2, av2a, av2b, WTv2, wav2a, wav2b, HD};
        WprepP w3{Wo2, ao2a, ao2b, WTo2, wao2a, wao2b, HD};
        wprep_k<<<25, 256, 0, stream>>>(w0, w1, w2, w3, 16, 17, 21);
    }
    // adjacency bitmasks (once, reused by both layers); word-per-thread, vectorized
    maskg_k<500, 16><<<(8 * 500 * 16 + 255) / 256, 256, 0, stream>>>(vis_adj, maskV);
    maskg_k<1500, 47><<<(8 * 1500 * 47 + 255) / 256, 256, 0, stream>>>(obj_adj, maskO);

    colsum_part_k<<<dim3((NV + 255) / 256, CCH, B), 256, 0, stream>>>(A_OV, s1p, B, NO, NV);
    colsum_fin_k<<<dim3((B * NV + 255) / 256), 256, 0, stream>>>(s1p, rs1, B, NV);
    rowsum_inv_k<<<dim3((B * NO + 3) / 4), 256, 0, stream>>>(A_OV, rs1, rs2, B, NO, NV);

    // geometry:
    const int tilesV32 = 16, tilesO32 = 47;          // ceil(N/32) agg i-tiles
    const int tilesV = 8, tilesO = 24;               // ceil(N/64) cross i-tiles
    const int SVO = 8, SOV = 4;
    const int tpsVO = 6;   // ceil(ceil(1500/32)/8)
    const int tpsOV = 4;   // ceil(ceil(500/32)/4)
    const int G_AGG_V = B * tilesV32;                // 128 (32-row full-row blocks)
    const int G_AGG_O = B * tilesO32;                // 376
    const int G_CR_VO = B * tilesV * SVO;            // 512
    const int G_CR_OV = B * tilesO * SOV;            // 768
    const int G_MLP_V = B * NV / 8;                  // 500
    const int G_MLP_O = B * NO / 8;                  // 1500
    const int G_XP_V = B * NV / 4;                   // 1000
    const int G_XP_O = B * NO / 4;                   // 3000
    const int G_GMF_V = B * tilesJV;                 // 128
    const int G_GMF_O = B * tilesJO;                 // 376

    // shared per-layer tail (everything after h/scores are computed)
    auto tail = [&](float* visout, float* objout) {
        sbmax2_k<<<16, 256, 0, stream>>>(sbV, smV, sbO, smO, NV, NO);
        AggP av{maskV, saV, sbV, smV, hTv, v1, NV, tilesV32, tilesJV};
        AggP ao{maskO, saO, sbO, smO, hTo, o1, NO, tilesO32, tilesJO};
        agg2_k<<<G_AGG_V + G_AGG_O, 128, 0, stream>>>(av, ao, G_AGG_V);
        CrossP cvo{A_OV, o1, nullptr, ppV, NV, NO, tilesV, tpsVO};
        CrossP cov{A_OV, v1, rs1, ppO, NO, NV, tilesO, tpsOV};
        cross2_k<<<G_CR_VO + G_CR_OV, THR, 0, stream>>>(cvo, cov, G_CR_VO);
        MlpP mv{ppV, rs1, SVO, o2g_W1, o2g_b1, o2g_W2, o2g_b2, v1, visout, B * NV};
        MlpP mo{ppO, rs2, SOV, g2o_W1, g2o_b1, g2o_W2, g2o_b2, o1, objout, B * NO};
        mlp2_k<<<G_MLP_V + G_MLP_O, 128, 0, stream>>>(mv, mo, G_MLP_V);
    };

    // ---- layer 1 (Kv=512, Ko=32) ----
    {
        XprepP xv{vis_memory, XbfV, wav1a, wav1b, saV, sbV, B * NV};
        XprepP xo{obj_memory, XbfO, wao1a, wao1b, saO, sbO, B * NO};
        xprep2_k<512, 32><<<G_XP_V + G_XP_O, 256, 0, stream>>>(xv, xo, G_XP_V);
        GmfP gv{XbfV, WTv1, hTv, NV, tilesJV};
        GmfP go{XbfO, WTo1, hTo, NO, tilesJO};
        gmf2_k<512, 32><<<G_GMF_V + G_GMF_O, 256, 0, stream>>>(gv, go, G_GMF_V);
        tail(visb, objb);
    }
    // ---- layer 2 (Kv=Ko=128) ----
    {
        XprepP xv{visb, XbfV, wav2a, wav2b, saV, sbV, B * NV};
        XprepP xo{objb, XbfO, wao2a, wao2b, saO, sbO, B * NO};
        xprep2_k<128, 128><<<G_XP_V + G_XP_O, 256, 0, stream>>>(xv, xo, G_XP_V);
        GmfP gv{XbfV, WTv2, hTv, NV, tilesJV};
        GmfP go{XbfO, WTo2, hTo, NO, tilesJO};
        gmf2_k<128, 128><<<G_GMF_V + G_GMF_O, 256, 0, stream>>>(gv, go, G_GMF_V);
        tail(visb, objb);
    }

    // output projections
    float* vis_out = (float*)d_out;
    float* obj_out = vis_out + (size_t)B * NV * DV;
    linear_k<0, 1, 0><<<dim3((B * NV + 3) / 4, (DV + 255) / 256), 128, 0, stream>>>(
        visb, img_W, img_b, nullptr, vis_out, B * NV, HD, DV);
    linear_k<0, 1, 0><<<dim3((B * NO + 3) / 4, 1), 128, 0, stream>>>(
        objb, obj_W, obj_b, nullptr, obj_out, B * NO, HD, DO);
}

// Round 6
// 529.475 us; speedup vs baseline: 1.1981x; 1.1125x over previous
//
#include <hip/hip_runtime.h>
#include <math.h>

#define EPSV 1e-5f
#define HD 128
#define CCH 16

typedef __attribute__((address_space(3))) uint32_t lds_u32_t;
typedef __attribute__((address_space(1))) uint32_t gbl_u32_t;
typedef __attribute__((ext_vector_type(8))) short bf16x8;
typedef __attribute__((ext_vector_type(4))) float f32x4;

__device__ __forceinline__ void async_copy16(const float* g, float* l) {
    __builtin_amdgcn_global_load_lds((const gbl_u32_t*)g, (lds_u32_t*)l, 16, 0, 0);
}

// stage an 8 KB bf16 tile global -> LDS via async DMA (128 threads, 4 insts each)
__device__ __forceinline__ void stage_8k_128(const void* g, void* l, int t) {
    const float* gf = (const float*)g; float* lf = (float*)l;
    async_copy16(gf + t * 4, lf + t * 4);
    async_copy16(gf + t * 4 + 512, lf + t * 4 + 512);
    async_copy16(gf + t * 4 + 1024, lf + t * 4 + 1024);
    async_copy16(gf + t * 4 + 1536, lf + t * 4 + 1536);
}

__device__ __forceinline__ unsigned int f2bf(float f) {
    return __builtin_bit_cast(unsigned int, f) >> 16;
}

// round-to-nearest-even fp32 -> bf16
__device__ __forceinline__ unsigned short rne_bf16(float f) {
    unsigned int u = __builtin_bit_cast(unsigned int, f);
    u += 0x7FFFu + ((u >> 16) & 1u);
    return (unsigned short)(u >> 16);
}

__device__ __forceinline__ bf16x8 pack8_rne(const float* w) {
    unsigned int u0 = (unsigned int)rne_bf16(w[0]) | ((unsigned int)rne_bf16(w[1]) << 16);
    unsigned int u1 = (unsigned int)rne_bf16(w[2]) | ((unsigned int)rne_bf16(w[3]) << 16);
    unsigned int u2 = (unsigned int)rne_bf16(w[4]) | ((unsigned int)rne_bf16(w[5]) << 16);
    unsigned int u3 = (unsigned int)rne_bf16(w[6]) | ((unsigned int)rne_bf16(w[7]) << 16);
    uint4 af = make_uint4(u0, u1, u2, u3);
    return __builtin_bit_cast(bf16x8, af);
}

// ---------------- param structs ----------------
struct WprepP { const float *W, *a1, *a2; unsigned short* WT; float *wa1, *wa2; int K; };
struct XprepP { const float* X; unsigned short* Xbf; const float *wa1, *wa2;
                float *sa, *sb; int rows; };
struct GmfP   { const unsigned short *Xbf, *WT; unsigned short* hT; int N, tilesJ; };
struct AggP  { const unsigned int* mask; const float *sa, *sb, *sm; const unsigned short* hT;
               float* out; unsigned short* hTout; const float* rsc; int N, tiles, tilesJ; };
struct CrossP{ const float* A; const unsigned short* hT; const float* rs_row;
               float* out; int iN, jN, tilesI, T; };
struct MlpP  { const float *pp, *scale; int S; const float *W1, *b1, *W2, *b2, *res;
               float *out; int rows; };

// ---------------- normalization scale kernels ----------------

__global__ void colsum_part_k(const float* __restrict__ A, float* __restrict__ s1p,
                              int B, int NO, int NV) {
    int v = blockIdx.x * 256 + threadIdx.x;
    int c = blockIdx.y, b = blockIdx.z;
    if (v >= NV) return;
    int chunk = (NO + CCH - 1) / CCH;
    int o0 = c * chunk;
    int o1 = o0 + chunk; if (o1 > NO) o1 = NO;
    const float* Ab = A + (size_t)b * NO * NV + v;
    float s = 0.f;
    for (int o = o0; o < o1; ++o) s += Ab[(size_t)o * NV];
    s1p[((size_t)b * CCH + c) * NV + v] = s;
}

__global__ void colsum_fin_k(const float* __restrict__ s1p, float* __restrict__ rs1,
                             int B, int NV) {
    int idx = blockIdx.x * 256 + threadIdx.x;
    if (idx >= B * NV) return;
    int b = idx / NV, v = idx - b * NV;
    float s = 0.f;
    for (int c = 0; c < CCH; ++c) s += s1p[((size_t)b * CCH + c) * NV + v];
    rs1[idx] = 1.f / (s + EPSV);
}

__global__ void rowsum_inv_k(const float* __restrict__ A, const float* __restrict__ rs1,
                             float* __restrict__ rs2, int B, int NO, int NV) {
    int row = blockIdx.x * (blockDim.x >> 6) + (threadIdx.x >> 6);
    int lane = threadIdx.x & 63;
    if (row >= B * NO) return;
    int b = row / NO;
    const float* Ar = A + (size_t)row * NV;
    const float* r1 = rs1 + (size_t)b * NV;
    float s = 0.f;
    for (int v = lane; v < NV; v += 64) s += Ar[v] * r1[v];
    for (int off = 32; off; off >>= 1) s += __shfl_xor(s, off, 64);
    if (lane == 0) rs2[row] = 1.f / (s + EPSV);
}

// ---------------- adjacency bitmask generation (runs once, both layers reuse) ----
// maskT layout: [b][word][i] u32, bit(j&31) = adj[b][i][word*32+j&31] > 0.
template<int N, int TILESJ>
__global__ __launch_bounds__(256)
void maskg_k(const float* __restrict__ adj, unsigned int* __restrict__ maskT) {
    int tid = blockIdx.x * 256 + threadIdx.x;
    int w = tid % TILESJ;
    int rowid = tid / TILESJ;                        // b*N + i
    if (rowid >= 8 * N) return;
    int b = rowid / N, i = rowid - b * N;
    int j0 = w * 32;
    const float* src = adj + (size_t)rowid * N + j0;
    unsigned int bits = 0u;
    if (j0 + 32 <= N) {
#pragma unroll
        for (int q = 0; q < 8; ++q) {
            float4 v = ((const float4*)src)[q];
            bits |= (v.x > 0.f ? 1u : 0u) << (q * 4 + 0);
            bits |= (v.y > 0.f ? 1u : 0u) << (q * 4 + 1);
            bits |= (v.z > 0.f ? 1u : 0u) << (q * 4 + 2);
            bits |= (v.w > 0.f ? 1u : 0u) << (q * 4 + 3);
        }
    } else {
#pragma unroll
        for (int r = 0; r < 32; ++r)
            if (j0 + r < N) bits |= (src[r] > 0.f ? 1u : 0u) << r;
    }
    maskT[((size_t)b * TILESJ + w) * N + i] = bits;
}

// ---------------- weight prep (runs once): WT[c][k] bf16 + wa1/wa2 = W @ a ----------
__global__ __launch_bounds__(256)
void wprep_k(WprepP p0, WprepP p1, WprepP p2, WprepP p3, int e0, int e1, int e2) {
    __shared__ float lw[32][129];
    __shared__ float a1s[128], a2s[128];
    int bid = blockIdx.x;
    const WprepP& P = bid < e0 ? p0 : bid < e1 ? p1 : bid < e2 ? p2 : p3;
    int lb = bid < e0 ? bid : bid < e1 ? bid - e0 : bid < e2 ? bid - e1 : bid - e2;
    int k0 = lb * 32, K = P.K;
    int t = threadIdx.x;
    if (t < 128) { a1s[t] = P.a1[t]; a2s[t] = P.a2[t]; }
    for (int idx = t; idx < 32 * 32; idx += 256) {   // float4 granularity
        int kk = idx >> 5, c4 = idx & 31;
        float4 v = ((const float4*)(P.W + (size_t)(k0 + kk) * 128))[c4];
        lw[kk][c4 * 4 + 0] = v.x; lw[kk][c4 * 4 + 1] = v.y;
        lw[kk][c4 * 4 + 2] = v.z; lw[kk][c4 * 4 + 3] = v.w;
    }
    __syncthreads();
    // wa1/wa2: 8 lanes per k-row
    int kk = t >> 3, g = t & 7;
    float s1 = 0.f, s2 = 0.f;
    for (int c = g; c < 128; c += 8) {
        float w = lw[kk][c];
        s1 = fmaf(w, a1s[c], s1);
        s2 = fmaf(w, a2s[c], s2);
    }
    s1 += __shfl_xor(s1, 1, 64); s1 += __shfl_xor(s1, 2, 64); s1 += __shfl_xor(s1, 4, 64);
    s2 += __shfl_xor(s2, 1, 64); s2 += __shfl_xor(s2, 2, 64); s2 += __shfl_xor(s2, 4, 64);
    if (g == 0) { P.wa1[k0 + kk] = s1; P.wa2[k0 + kk] = s2; }
    // transposed bf16 store: WT[c][k]
    for (int idx = t; idx < 4096; idx += 256) {
        int c = idx >> 5, k = idx & 31;
        P.WT[(size_t)c * K + k0 + k] = rne_bf16(lw[k][c]);
    }
}

// ---------------- X prep: Xbf = rne_bf16(X); sa = X.wa1, sb = X.wa2 (exact fp32) ----
template<int K>
__device__ void xprep_body(const XprepP& P, int lb) {
    int t = threadIdx.x, wv = t >> 6, lane = t & 63;
    int row = lb * 4 + wv;
    if (row >= P.rows) return;
    const float4* x4 = (const float4*)(P.X + (size_t)row * K);
    const float4* w14 = (const float4*)P.wa1;
    const float4* w24 = (const float4*)P.wa2;
    unsigned short* xb = P.Xbf + (size_t)row * K;
    float s1 = 0.f, s2 = 0.f;
    constexpr int K4 = K / 4;
    constexpr int NI = (K4 + 63) / 64;
#pragma unroll
    for (int i = 0; i < NI; ++i) {
        int k4 = i * 64 + lane;
        if ((K4 % 64 == 0) || (k4 < K4)) {
            float4 x = x4[k4];
            float4 a = w14[k4];
            float4 b = w24[k4];
            s1 += x.x * a.x + x.y * a.y + x.z * a.z + x.w * a.w;
            s2 += x.x * b.x + x.y * b.y + x.z * b.z + x.w * b.w;
            ushort4 p = make_ushort4(rne_bf16(x.x), rne_bf16(x.y),
                                     rne_bf16(x.z), rne_bf16(x.w));
            *(ushort4*)(xb + (size_t)k4 * 4) = p;
        }
    }
#pragma unroll
    for (int off = 32; off; off >>= 1) {
        s1 += __shfl_xor(s1, off, 64);
        s2 += __shfl_xor(s2, off, 64);
    }
    if (lane == 0) { P.sa[row] = s1; P.sb[row] = s2; }
}

template<int KV, int KO>
__global__ __launch_bounds__(256)
void xprep2_k(XprepP V, XprepP O, int GV) {
    int bid = blockIdx.x;
    if (bid < GV) xprep_body<KV>(V, bid);
    else          xprep_body<KO>(O, bid - GV);
}

// ---------------- MFMA h-GEMM producing hT directly (bank-swizzled layout) --------
// D[m=c][n=jl] = sum_k WT[c][k] * Xbf[row0+jl][k]  via mfma_f32_16x16x32_bf16.
// hT tile layout is SWIZZLED: element (c, jl) at ushort index c*32 + (jl ^ (((c>>1)&3)<<3)).
template<int K>
__device__ void gmf_body(const GmfP& P, int lb) {
    int tilesJ = P.tilesJ, N = P.N;
    int b = lb / tilesJ, jt = lb - b * tilesJ;
    int t = threadIdx.x, wv = t >> 6, lane = t & 63;
    int ml = lane & 15, quad = lane >> 4;
    const unsigned short* xb = P.Xbf + ((size_t)b * N + (size_t)jt * 32) * K;
    const unsigned short* wt0 = P.WT + (size_t)(wv * 32 + ml) * K;
    const unsigned short* wt1 = wt0 + (size_t)16 * K;
    const unsigned short* xb0 = xb + (size_t)ml * K;
    const unsigned short* xb1 = xb + (size_t)(16 + ml) * K;
    f32x4 acc00 = {0.f, 0.f, 0.f, 0.f}, acc01 = acc00, acc10 = acc00, acc11 = acc00;
#pragma unroll 4
    for (int kt = 0; kt < K / 32; ++kt) {
        int kk = kt * 32 + quad * 8;
        bf16x8 a0 = *(const bf16x8*)(wt0 + kk);
        bf16x8 a1 = *(const bf16x8*)(wt1 + kk);
        bf16x8 b0 = *(const bf16x8*)(xb0 + kk);
        bf16x8 b1 = *(const bf16x8*)(xb1 + kk);
        acc00 = __builtin_amdgcn_mfma_f32_16x16x32_bf16(a0, b0, acc00, 0, 0, 0);
        acc01 = __builtin_amdgcn_mfma_f32_16x16x32_bf16(a0, b1, acc01, 0, 0, 0);
        acc10 = __builtin_amdgcn_mfma_f32_16x16x32_bf16(a1, b0, acc10, 0, 0, 0);
        acc11 = __builtin_amdgcn_mfma_f32_16x16x32_bf16(a1, b1, acc11, 0, 0, 0);
    }
    unsigned short* hb = P.hT + (size_t)(b * tilesJ + jt) * 4096;
    int nvalid = N - jt * 32; if (nvalid > 32) nvalid = 32;
    bool ok0 = ml < nvalid, ok1 = (16 + ml) < nvalid;
    int c0 = wv * 32 + quad * 4;
#pragma unroll
    for (int r = 0; r < 4; ++r) {
        int ca = c0 + r, cb = c0 + 16 + r;
        int swa = ((ca >> 1) & 3) << 3, swb = ((cb >> 1) & 3) << 3;
        hb[ca * 32 + (ml ^ swa)]        = ok0 ? rne_bf16(acc00[r]) : 0;
        hb[ca * 32 + ((16 + ml) ^ swa)] = ok1 ? rne_bf16(acc01[r]) : 0;
        hb[cb * 32 + (ml ^ swb)]        = ok0 ? rne_bf16(acc10[r]) : 0;
        hb[cb * 32 + ((16 + ml) ^ swb)] = ok1 ? rne_bf16(acc11[r]) : 0;
    }
}

template<int KV, int KO>
__global__ __launch_bounds__(256)
void gmf2_k(GmfP V, GmfP O, int GV) {
    int bid = blockIdx.x;
    if (bid < GV) gmf_body<KV>(V, bid);
    else          gmf_body<KO>(O, bid - GV);
}

// ---------------- fused per-batch sb max ----------------
__global__ __launch_bounds__(256)
void sbmax2_k(const float* __restrict__ sbV, float* __restrict__ smV,
              const float* __restrict__ sbO, float* __restrict__ smO,
              int NV, int NO) {
    __shared__ float red[256];
    int b0 = blockIdx.x, t = threadIdx.x;
    const float* sb; float* out; int N;
    if (b0 < 8) { sb = sbV + (size_t)b0 * NV; out = smV + b0; N = NV; }
    else        { sb = sbO + (size_t)(b0 - 8) * NO; out = smO + (b0 - 8); N = NO; }
    float m = -INFINITY;
    for (int j = t; j < N; j += 256) m = fmaxf(m, sb[j]);
    red[t] = m; __syncthreads();
    for (int s = 128; s; s >>= 1) {
        if (t < s) red[t] = fmaxf(red[t], red[t + s]);
        __syncthreads();
    }
    if (t == 0) *out = red[0];
}

// ---------------- MFMA GAT aggregation, FULL-ROW, 32-row blocks ----------------
// 128 threads (2 waves); per-lane A-fragment w's computed directly. hT DMA depth-4
// over 5 buffers, counted vmcnt. Epilogue: /z, relu -> fp32 out AND bf16 hT-layout
// tile (hTout, optionally pre-scaled by rsc) for the MFMA cross kernels.
struct SharedAgg32 {
    unsigned short hsT[5][128][32];    // [c][jl-swz] bf16, DMA'd from hT (5-deep)
    unsigned int mask_s[48][32];       // [tile][row] adjacency bits
    float sb_s[48 * 32];               // sb for the whole j-range
    float z_s[32];
};

__device__ void agg_body(SharedAgg32& sm, const AggP& P, int lbid) {
    int tiles = P.tiles;                             // ceil(N/32)
    int b = lbid / tiles;
    int jt_i = lbid - b * tiles;
    int i0 = jt_i * 32;
    int N = P.N, T = P.tilesJ;
    int t = threadIdx.x;
    int wv = t >> 6, lane = t & 63, quad = lane >> 4, ml = lane & 15;
    // stage mask (uint4) + sb (float4); OOB reads land in workspace pad (benign)
    const unsigned int* mb = P.mask + (size_t)b * T * N + i0;
    for (int idx = t; idx < T * 8; idx += 128) {
        int w = idx >> 3, r4 = idx & 7;
        *(uint4*)&sm.mask_s[w][r4 * 4] = *(const uint4*)&mb[(size_t)w * N + r4 * 4];
    }
    const float* sbb = P.sb + (size_t)b * N;
    for (int idx = t; idx < T * 8; idx += 128)
        ((float4*)sm.sb_s)[idx] = ((const float4*)sbb)[idx];
    // per-lane row state (reg-resident)
    int row_loc = wv * 16 + ml;
    int irow = i0 + row_loc;
    float sa = (irow < N) ? P.sa[(size_t)b * N + irow] : 0.f;
    float e0 = sa + P.sm[b];
    float m = e0 > 0.f ? e0 : 0.2f * e0;
    __syncthreads();                                 // mask_s/sb_s visible
    // prologue: DMA tiles 0..3 (depth-4)
    const unsigned short* hTb = P.hT + (size_t)b * T * 4096;
    stage_8k_128(hTb, &sm.hsT[0][0][0], t);
    if (T > 1) stage_8k_128(hTb + 4096, &sm.hsT[1][0][0], t);
    if (T > 2) stage_8k_128(hTb + 8192, &sm.hsT[2][0][0], t);
    if (T > 3) stage_8k_128(hTb + 12288, &sm.hsT[3][0][0], t);

    int nq2 = (quad ^ ((ml >> 1) & 3)) * 8;          // B-frag granule (swizzle fold)
    f32x4 acc[8];
#pragma unroll
    for (int nt = 0; nt < 8; ++nt)
#pragma unroll
        for (int r = 0; r < 4; ++r) acc[nt][r] = 0.f;
    float zacc = 0.f;
    for (int tt = 0; tt < T; ++tt) {
        int cur = tt - (tt / 5) * 5;                 // tt % 5
        unsigned int mq = sm.mask_s[tt][row_loc] >> (quad * 8);
        float4 s0 = *(const float4*)&sm.sb_s[tt * 32 + quad * 8];
        float4 s1 = *(const float4*)&sm.sb_s[tt * 32 + quad * 8 + 4];
        float sv[8] = {s0.x, s0.y, s0.z, s0.w, s1.x, s1.y, s1.z, s1.w};
        float w_[8];
#pragma unroll
        for (int i = 0; i < 8; ++i) {
            float e = sa + sv[i];
            e = e > 0.f ? e : 0.2f * e;
            float ww = __expf(e - m);
            ww = ((mq >> i) & 1u) ? ww : 0.f;
            zacc += ww;
            w_[i] = ww;
        }
        unsigned int u0 = f2bf(w_[0]) | (__builtin_bit_cast(unsigned int, w_[1]) & 0xFFFF0000u);
        unsigned int u1 = f2bf(w_[2]) | (__builtin_bit_cast(unsigned int, w_[3]) & 0xFFFF0000u);
        unsigned int u2 = f2bf(w_[4]) | (__builtin_bit_cast(unsigned int, w_[5]) & 0xFFFF0000u);
        unsigned int u3 = f2bf(w_[6]) | (__builtin_bit_cast(unsigned int, w_[7]) & 0xFFFF0000u);
        uint4 af = make_uint4(u0, u1, u2, u3);
        bf16x8 afrag = __builtin_bit_cast(bf16x8, af);
        // counted drain: keep up to 3 future stages (12 vm ops) in flight
        int rem = T - tt;
        if (rem >= 4)      asm volatile("s_waitcnt vmcnt(12)" ::: "memory");
        else if (rem == 3) asm volatile("s_waitcnt vmcnt(8)" ::: "memory");
        else if (rem == 2) asm volatile("s_waitcnt vmcnt(4)" ::: "memory");
        else               asm volatile("s_waitcnt vmcnt(0)" ::: "memory");
        __builtin_amdgcn_s_barrier();
        asm volatile("" ::: "memory");
        if (tt + 4 < T) {
            int nb = tt + 4; nb -= (nb / 5) * 5;
            stage_8k_128(hTb + (size_t)(tt + 4) * 4096, &sm.hsT[nb][0][0], t);
        }
#pragma unroll
        for (int nt = 0; nt < 8; ++nt) {
            bf16x8 bfrag = *(const bf16x8*)&sm.hsT[cur][nt * 16 + ml][nq2];
            acc[nt] = __builtin_amdgcn_mfma_f32_16x16x32_bf16(afrag, bfrag, acc[nt], 0, 0, 0);
        }
    }
    // z: reduce over 4 quads sharing a row
    zacc += __shfl_xor(zacc, 16, 64);
    zacc += __shfl_xor(zacc, 32, 64);
    if (quad == 0) sm.z_s[row_loc] = zacc;
    __syncthreads();
    // epilogue: /z, relu -> fp32 final store + bf16 hT-tile (zero-padded, swizzled)
    float* outb = P.out + (size_t)b * N * HD;
    unsigned short* hb = P.hTout + ((size_t)b * tiles + jt_i) * 4096;
#pragma unroll
    for (int r = 0; r < 4; ++r) {
        int rr = wv * 16 + quad * 4 + r;
        float inv = 1.f / sm.z_s[rr];
        int row = i0 + rr;
        bool ok = row < N;
        float sc = 1.f;
        if (P.rsc != nullptr && ok) sc = P.rsc[(size_t)b * N + row];
#pragma unroll
        for (int nt = 0; nt < 8; ++nt) {
            float val = fmaxf(acc[nt][r] * inv, 0.f);
            if (ok) outb[(size_t)row * HD + nt * 16 + ml] = val;
            int c = nt * 16 + ml;
            int sw = ((c >> 1) & 3) << 3;
            hb[c * 32 + (rr ^ sw)] = ok ? rne_bf16(val * sc) : (unsigned short)0;
        }
    }
}

__global__ __launch_bounds__(128)
void agg2_k(AggP V, AggP O, int GVb) {
    __shared__ SharedAgg32 sm;
    int bid = blockIdx.x;
    if (bid < GVb) agg_body(sm, V, bid);
    else           agg_body(sm, O, bid - GVb);
}

// ---------------- MFMA cross (vo + ov), FULL-ROW, 32-row blocks ----------------
// Same engine as agg: out[32 x 128] = W[32 x jN] @ H[jN x 128], W = raw adjacency
// values (bf16, rne), H = bf16 hT tiles produced by agg epilogue (vis copy is
// rs1-prescaled). Per-row scale (rs1 / rs2) applied at the fp32 epilogue, which
// writes the FINAL MLP input (no partials). A prefetched depth-2 in registers;
// hT DMA depth-4 over 5 buffers. Uniform vm-issue per iteration (dummy tail
// loads) => single counted vmcnt per iter, provably draining DMA(tt) (FIFO).
struct SharedCr { unsigned short hsT[5][128][32]; };

__device__ void cross_vo_body(SharedCr& sm, const CrossP& P, int lbid) {
    int tiles = P.tilesI;
    int b = lbid / tiles;
    int i0 = (lbid - b * tiles) * 32;
    int iN = P.iN, jN = P.jN, T = P.T;
    int t = threadIdx.x, wv = t >> 6, lane = t & 63, quad = lane >> 4, ml = lane & 15;
    int row_loc = wv * 16 + ml;
    int irow = i0 + row_loc;
    int ivc = irow < iN ? irow : iN - 1;
    const float* Ab = P.A + (size_t)b * jN * iN;      // A[o][v], row-stride iN
    const unsigned short* hTb = P.hT + (size_t)b * T * 4096;
    float wA[8], wB[8];
#define VO_LOAD(W_, jt_) do { int _o0 = (jt_) * 32 + quad * 8;                     \
    _Pragma("unroll") for (int _i = 0; _i < 8; ++_i) {                             \
        int _o = _o0 + _i; _o = _o < jN ? _o : jN - 1;                             \
        W_[_i] = Ab[(size_t)_o * iN + ivc]; } } while (0)
    // uniform prologue: 4 virtual iters, each [DMA(4 ops), A-load(8 ops)]
    stage_8k_128(hTb,            &sm.hsT[0][0][0], t); VO_LOAD(wA, 0);   // dummy
    stage_8k_128(hTb + 4096,     &sm.hsT[1][0][0], t); VO_LOAD(wB, 0);   // dummy
    stage_8k_128(hTb + 2 * 4096, &sm.hsT[2][0][0], t); VO_LOAD(wA, 0);   // A(0)
    stage_8k_128(hTb + 3 * 4096, &sm.hsT[3][0][0], t); VO_LOAD(wB, 1);   // A(1)
    int nq2 = (quad ^ ((ml >> 1) & 3)) * 8;
    f32x4 acc[8];
#pragma unroll
    for (int nt = 0; nt < 8; ++nt)
#pragma unroll
        for (int r = 0; r < 4; ++r) acc[nt][r] = 0.f;
#define CR_VO_TILE(tt_, W_) do {                                                   \
    bf16x8 afrag_ = pack8_rne(W_);                                                 \
    /* 44 vm ops issued after DMA(tt_) (uniform stream) -> FIFO-drains DMA(tt_) */ \
    asm volatile("s_waitcnt vmcnt(44)" ::: "memory");                              \
    __builtin_amdgcn_s_barrier();                                                  \
    asm volatile("" ::: "memory");                                                 \
    { int _srct = (tt_) + 4 < T ? (tt_) + 4 : T - 1;                               \
      int _dbuf = (tt_) + 4; _dbuf -= (_dbuf / 5) * 5;                             \
      stage_8k_128(hTb + (size_t)_srct * 4096, &sm.hsT[_dbuf][0][0], t); }         \
    { int _at = (tt_) + 2 < T ? (tt_) + 2 : T - 1;                                 \
      VO_LOAD(W_, _at); }                                                          \
    { int _cur = (tt_); _cur -= (_cur / 5) * 5;                                    \
      _Pragma("unroll")                                                            \
      for (int nt = 0; nt < 8; ++nt) {                                             \
          bf16x8 bfrag_ = *(const bf16x8*)&sm.hsT[_cur][nt * 16 + ml][nq2];        \
          acc[nt] = __builtin_amdgcn_mfma_f32_16x16x32_bf16(afrag_, bfrag_, acc[nt], 0, 0, 0); \
      } }                                                                          \
} while (0)
    int tt = 0;
    while (true) {
        CR_VO_TILE(tt, wA); ++tt; if (tt >= T) break;
        CR_VO_TILE(tt, wB); ++tt; if (tt >= T) break;
    }
#undef CR_VO_TILE
#undef VO_LOAD
    asm volatile("s_waitcnt vmcnt(0)" ::: "memory");  // drain dangling dummy DMAs
    float* outb = P.out + (size_t)b * iN * HD;
#pragma unroll
    for (int r = 0; r < 4; ++r) {
        int rr = wv * 16 + quad * 4 + r;
        int row = i0 + rr;
        if (row < iN) {
            float s = P.rs_row[(size_t)b * iN + row];
#pragma unroll
            for (int nt = 0; nt < 8; ++nt)
                outb[(size_t)row * HD + nt * 16 + ml] = acc[nt][r] * s;
        }
    }
}

__device__ void cross_ov_body(SharedCr& sm, const CrossP& P, int lbid) {
    int tiles = P.tilesI;
    int b = lbid / tiles;
    int i0 = (lbid - b * tiles) * 32;
    int iN = P.iN, jN = P.jN, T = P.T;
    int t = threadIdx.x, wv = t >> 6, lane = t & 63, quad = lane >> 4, ml = lane & 15;
    int row_loc = wv * 16 + ml;
    int irow = i0 + row_loc;
    int ivc = irow < iN ? irow : iN - 1;
    const float* Ab = P.A + (size_t)b * iN * jN;      // A[o][v], row-stride jN
    const unsigned short* hTb = P.hT + (size_t)b * T * 4096;
    float wA[8], wB[8];
#define OV_LOAD(W_, jt_) do { int _v0 = (jt_) * 32 + quad * 8;                     \
    _v0 = _v0 + 8 <= jN ? _v0 : jN - 8;                                            \
    const float* _p = Ab + (size_t)ivc * jN + _v0;                                 \
    float4 _a = *(const float4*)_p; float4 _c = *(const float4*)(_p + 4);          \
    W_[0] = _a.x; W_[1] = _a.y; W_[2] = _a.z; W_[3] = _a.w;                        \
    W_[4] = _c.x; W_[5] = _c.y; W_[6] = _c.z; W_[7] = _c.w; } while (0)
    stage_8k_128(hTb,            &sm.hsT[0][0][0], t); OV_LOAD(wA, 0);   // dummy
    stage_8k_128(hTb + 4096,     &sm.hsT[1][0][0], t); OV_LOAD(wB, 0);   // dummy
    stage_8k_128(hTb + 2 * 4096, &sm.hsT[2][0][0], t); OV_LOAD(wA, 0);   // A(0)
    stage_8k_128(hTb + 3 * 4096, &sm.hsT[3][0][0], t); OV_LOAD(wB, 1);   // A(1)
    int nq2 = (quad ^ ((ml >> 1) & 3)) * 8;
    f32x4 acc[8];
#pragma unroll
    for (int nt = 0; nt < 8; ++nt)
#pragma unroll
        for (int r = 0; r < 4; ++r) acc[nt][r] = 0.f;
#define CR_OV_TILE(tt_, W_) do {                                                   \
    bf16x8 afrag_ = pack8_rne(W_);                                                 \
    /* 20 vm ops issued after DMA(tt_) (uniform 6-op stream) */                    \
    asm volatile("s_waitcnt vmcnt(20)" ::: "memory");                              \
    __builtin_amdgcn_s_barrier();                                                  \
    asm volatile("" ::: "memory");                                                 \
    { int _srct = (tt_) + 4 < T ? (tt_) + 4 : T - 1;                               \
      int _dbuf = (tt_) + 4; _dbuf -= (_dbuf / 5) * 5;                             \
      stage_8k_128(hTb + (size_t)_srct * 4096, &sm.hsT[_dbuf][0][0], t); }         \
    { int _at = (tt_) + 2 < T ? (tt_) + 2 : T - 1;                                 \
      OV_LOAD(W_, _at); }                                                          \
    { int _cur = (tt_); _cur -= (_cur / 5) * 5;                                    \
      _Pragma("unroll")                                                            \
      for (int nt = 0; nt < 8; ++nt) {                                             \
          bf16x8 bfrag_ = *(const bf16x8*)&sm.hsT[_cur][nt * 16 + ml][nq2];        \
          acc[nt] = __builtin_amdgcn_mfma_f32_16x16x32_bf16(afrag_, bfrag_, acc[nt], 0, 0, 0); \
      } }                                                                          \
} while (0)
    int tt = 0;
    while (true) {
        CR_OV_TILE(tt, wA); ++tt; if (tt >= T) break;
        CR_OV_TILE(tt, wB); ++tt; if (tt >= T) break;
    }
#undef CR_OV_TILE
#undef OV_LOAD
    asm volatile("s_waitcnt vmcnt(0)" ::: "memory");
    float* outb = P.out + (size_t)b * iN * HD;
#pragma unroll
    for (int r = 0; r < 4; ++r) {
        int rr = wv * 16 + quad * 4 + r;
        int row = i0 + rr;
        if (row < iN) {
            float s = P.rs_row[(size_t)b * iN + row];
#pragma unroll
            for (int nt = 0; nt < 8; ++nt)
                outb[(size_t)row * HD + nt * 16 + ml] = acc[nt][r] * s;
        }
    }
}

__global__ __launch_bounds__(128)
void cross2_k(CrossP VO, CrossP OV, int GVOb) {
    __shared__ SharedCr sm;
    int bid = blockIdx.x;
    if (bid < GVOb) cross_vo_body(sm, VO, bid);
    else            cross_ov_body(sm, OV, bid - GVOb);
}

// ---------------- fused MLP: out = (relu(x@W1+b1))@W2 + b2 + res ----------------
__global__ __launch_bounds__(128)
void mlp2_k(MlpP V, MlpP O, int GVb) {
    __shared__ float xs[8][HD];
    __shared__ float hh[8][HD];
    int bid = blockIdx.x;
    const MlpP& P = (bid < GVb) ? V : O;
    int row0 = ((bid < GVb) ? bid : bid - GVb) * 8;
    int rows = P.rows;
    int t = threadIdx.x;
    for (int l = t; l < 8 * 32; l += 128) {
        int r = l >> 5, c4 = l & 31;
        int row = row0 + r;
        float4 v = make_float4(0.f, 0.f, 0.f, 0.f);
        if (row < rows) {
            for (int s = 0; s < P.S; ++s) {
                float4 p = ((const float4*)P.pp)[((size_t)s * rows + row) * 32 + c4];
                v.x += p.x; v.y += p.y; v.z += p.z; v.w += p.w;
            }
            if (P.scale != nullptr) {
                float sc = P.scale[row];
                v.x *= sc; v.y *= sc; v.z *= sc; v.w *= sc;
            }
        }
        ((float4*)&xs[r][0])[c4] = v;
    }
    __syncthreads();
    int wv = t >> 6, tt = t & 63, rb = wv * 4;
    float a0[4] = {0.f, 0.f, 0.f, 0.f}, a1v[4] = {0.f, 0.f, 0.f, 0.f};
#pragma unroll 4
    for (int k = 0; k < HD; ++k) {
        float w0 = P.W1[(size_t)k * HD + tt];
        float w1 = P.W1[(size_t)k * HD + tt + 64];
#pragma unroll
        for (int r = 0; r < 4; ++r) {
            float x = xs[rb + r][k];
            a0[r] = fmaf(x, w0, a0[r]);
            a1v[r] = fmaf(x, w1, a1v[r]);
        }
    }
    float bb0 = P.b1[tt], bb1 = P.b1[tt + 64];
#pragma unroll
    for (int r = 0; r < 4; ++r) {
        hh[rb + r][tt]      = fmaxf(a0[r] + bb0, 0.f);
        hh[rb + r][tt + 64] = fmaxf(a1v[r] + bb1, 0.f);
    }
    __syncthreads();
    float c0a[4] = {0.f, 0.f, 0.f, 0.f}, c1a[4] = {0.f, 0.f, 0.f, 0.f};
#pragma unroll 4
    for (int k = 0; k < HD; ++k) {
        float w0 = P.W2[(size_t)k * HD + tt];
        float w1 = P.W2[(size_t)k * HD + tt + 64];
#pragma unroll
        for (int r = 0; r < 4; ++r) {
            float x = hh[rb + r][k];
            c0a[r] = fmaf(x, w0, c0a[r]);
            c1a[r] = fmaf(x, w1, c1a[r]);
        }
    }
    float d0 = P.b2[tt], d1 = P.b2[tt + 64];
#pragma unroll
    for (int r = 0; r < 4; ++r) {
        int row = row0 + rb + r;
        if (row >= rows) continue;
        P.out[(size_t)row * HD + tt]      = c0a[r] + d0 + P.res[(size_t)row * HD + tt];
        P.out[(size_t)row * HD + tt + 64] = c1a[r] + d1 + P.res[(size_t)row * HD + tt + 64];
    }
}

// ---------------- output projection ----------------
template<int RELU, int BIAS, int RES>
__global__ __launch_bounds__(128)
void linear_k(const float* __restrict__ X, const float* __restrict__ W,
              const float* __restrict__ bias, const float* __restrict__ res,
              float* __restrict__ out, int rows, int K, int Dout) {
    __shared__ float xs[4][512];
    int row0 = blockIdx.x * 4;
    int t = threadIdx.x;
    int K4 = K >> 2;
    for (int l = t; l < 4 * K4; l += 128) {
        int r = l / K4, c4 = l - r * K4;
        float4 val = make_float4(0.f, 0.f, 0.f, 0.f);
        if (row0 + r < rows) val = ((const float4*)(X + (size_t)(row0 + r) * K))[c4];
        ((float4*)&xs[r][0])[c4] = val;
    }
    __syncthreads();
    int chunk = Dout < 256 ? Dout : 256;
    int half = chunk >> 1;
    if (t >= half) return;
    int c0 = blockIdx.y * chunk + t;
    int c1 = c0 + half;
    float a00 = 0, a01 = 0, a02 = 0, a03 = 0, a10 = 0, a11 = 0, a12 = 0, a13 = 0;
#pragma unroll 4
    for (int k = 0; k < K; ++k) {
        float w0 = W[(size_t)k * Dout + c0];
        float w1 = W[(size_t)k * Dout + c1];
        float x0 = xs[0][k], x1 = xs[1][k], x2 = xs[2][k], x3 = xs[3][k];
        a00 = fmaf(x0, w0, a00); a01 = fmaf(x1, w0, a01);
        a02 = fmaf(x2, w0, a02); a03 = fmaf(x3, w0, a03);
        a10 = fmaf(x0, w1, a10); a11 = fmaf(x1, w1, a11);
        a12 = fmaf(x2, w1, a12); a13 = fmaf(x3, w1, a13);
    }
    float accs[2][4] = {{a00, a01, a02, a03}, {a10, a11, a12, a13}};
    int cs[2] = {c0, c1};
    for (int h = 0; h < 2; ++h) {
        float bv = BIAS ? bias[cs[h]] : 0.f;
        for (int r = 0; r < 4; ++r) {
            int row = row0 + r;
            if (row >= rows) continue;
            float v = accs[h][r] + bv;
            if (RES) v += res[(size_t)row * Dout + cs[h]];
            if (RELU) v = fmaxf(v, 0.f);
            out[(size_t)row * Dout + cs[h]] = v;
        }
    }
}

// ---------------- host launcher ----------------
extern "C" void kernel_launch(void* const* d_in, const int* in_sizes, int n_in,
                              void* d_out, int out_size, void* d_ws, size_t ws_size,
                              hipStream_t stream) {
    const int B = 8, NV = 500, NO = 1500, DV = 512, DO = 32;
    const float* vis_memory = (const float*)d_in[0];
    const float* obj_memory = (const float*)d_in[1];
    const float* vis_adj    = (const float*)d_in[2];
    const float* obj_adj    = (const float*)d_in[3];
    const float* A_OV       = (const float*)d_in[4];
    const float* Wv1  = (const float*)d_in[5];
    const float* av1a = (const float*)d_in[6];
    const float* av1b = (const float*)d_in[7];
    const float* Wv2  = (const float*)d_in[8];
    const float* av2a = (const float*)d_in[9];
    const float* av2b = (const float*)d_in[10];
    const float* Wo1  = (const float*)d_in[11];
    const float* ao1a = (const float*)d_in[12];
    const float* ao1b = (const float*)d_in[13];
    const float* Wo2  = (const float*)d_in[14];
    const float* ao2a = (const float*)d_in[15];
    const float* ao2b = (const float*)d_in[16];
    const float* g2o_W1 = (const float*)d_in[17];
    const float* g2o_b1 = (const float*)d_in[18];
    const float* g2o_W2 = (const float*)d_in[19];
    const float* g2o_b2 = (const float*)d_in[20];
    const float* o2g_W1 = (const float*)d_in[21];
    const float* o2g_b1 = (const float*)d_in[22];
    const float* o2g_W2 = (const float*)d_in[23];
    const float* o2g_b2 = (const float*)d_in[24];
    const float* img_W = (const float*)d_in[25];
    const float* img_b = (const float*)d_in[26];
    const float* obj_W = (const float*)d_in[27];
    const float* obj_b = (const float*)d_in[28];

    const int tilesJV = 16, tilesJO = 47;            // ceil(N/32)

    float* wsp = (float*)d_ws;
    size_t off = 0;
    auto alloc = [&](size_t n) { float* p = wsp + off; off += (n + 3) & ~(size_t)3; return p; };
    float* rs1   = alloc(B * NV);
    float* rs2   = alloc(B * NO);
    float* saV   = alloc(B * NV);
    float* sbV   = alloc(B * NV);
    float* smV   = alloc(B);
    float* saO   = alloc(B * NO);
    float* sbO   = alloc(B * NO);
    float* smO   = alloc(B);
    float* s1p   = alloc((size_t)B * CCH * NV);
    // adjacency bitmasks (transposed [b][word][i], u32)
    unsigned int* maskV = (unsigned int*)alloc((size_t)B * tilesJV * NV);
    unsigned int* maskO = (unsigned int*)alloc((size_t)B * tilesJO * NO);
    // weight-prep outputs (bf16 transposed W + score vectors)
    unsigned short* WTv1 = (unsigned short*)alloc(128 * 512 / 2);
    unsigned short* WTo1 = (unsigned short*)alloc(128 * 32 / 2);
    unsigned short* WTv2 = (unsigned short*)alloc(128 * 128 / 2);
    unsigned short* WTo2 = (unsigned short*)alloc(128 * 128 / 2);
    float* wav1a = alloc(512); float* wav1b = alloc(512);
    float* wao1a = alloc(32);  float* wao1b = alloc(32);
    float* wav2a = alloc(128); float* wav2b = alloc(128);
    float* wao2a = alloc(128); float* wao2b = alloc(128);
    // bf16 X buffers (max over layers: vis 4000x512, obj 12000x128)
    unsigned short* XbfV = (unsigned short*)alloc((size_t)B * NV * 512 / 2);
    unsigned short* XbfO = (unsigned short*)alloc((size_t)B * NO * 128 / 2);
    unsigned short* hTv = (unsigned short*)alloc((size_t)B * tilesJV * 4096 / 2);
    unsigned short* hTo = (unsigned short*)alloc((size_t)B * tilesJO * 4096 / 2);
    // bf16 GAT-output tiles for MFMA cross (hTv2 is rs1-prescaled)
    unsigned short* hTv2 = (unsigned short*)alloc((size_t)B * tilesJV * 4096 / 2);
    unsigned short* hTo2 = (unsigned short*)alloc((size_t)B * tilesJO * 4096 / 2);
    float* v1    = alloc((size_t)B * NV * HD);
    float* o1    = alloc((size_t)B * NO * HD);
    float* visb  = alloc((size_t)B * NV * HD);
    float* objb  = alloc((size_t)B * NO * HD);
    float* ppV   = alloc((size_t)B * NV * HD);       // cross vis output (MLP input)
    float* ppO   = alloc((size_t)B * NO * HD);       // cross obj output (MLP input)
    alloc(16384);                                    // tail pad for async/OOB reads

    // weight prep (once): 16 + 1 + 4 + 4 = 25 blocks
    {
        WprepP w0{Wv1, av1a, av1b, WTv1, wav1a, wav1b, DV};
        WprepP w1{Wo1, ao1a, ao1b, WTo1, wao1a, wao1b, DO};
        WprepP w2{Wv2, av2a, av2b, WTv2, wav2a, wav2b, HD};
        WprepP w3{Wo2, ao2a, ao2b, WTo2, wao2a, wao2b, HD};
        wprep_k<<<25, 256, 0, stream>>>(w0, w1, w2, w3, 16, 17, 21);
    }
    // adjacency bitmasks (once, reused by both layers); word-per-thread, vectorized
    maskg_k<500, 16><<<(8 * 500 * 16 + 255) / 256, 256, 0, stream>>>(vis_adj, maskV);
    maskg_k<1500, 47><<<(8 * 1500 * 47 + 255) / 256, 256, 0, stream>>>(obj_adj, maskO);

    colsum_part_k<<<dim3((NV + 255) / 256, CCH, B), 256, 0, stream>>>(A_OV, s1p, B, NO, NV);
    colsum_fin_k<<<dim3((B * NV + 255) / 256), 256, 0, stream>>>(s1p, rs1, B, NV);
    rowsum_inv_k<<<dim3((B * NO + 3) / 4), 256, 0, stream>>>(A_OV, rs1, rs2, B, NO, NV);

    // geometry (32-row i-tiles everywhere):
    const int G_AGG_V = B * tilesJV;                 // 128
    const int G_AGG_O = B * tilesJO;                 // 376
    const int G_CR_VO = B * tilesJV;                 // 128
    const int G_CR_OV = B * tilesJO;                 // 376
    const int G_MLP_V = B * NV / 8;                  // 500
    const int G_MLP_O = B * NO / 8;                  // 1500
    const int G_XP_V = B * NV / 4;                   // 1000
    const int G_XP_O = B * NO / 4;                   // 3000
    const int G_GMF_V = B * tilesJV;                 // 128
    const int G_GMF_O = B * tilesJO;                 // 376

    // shared per-layer tail (everything after h/scores are computed)
    auto tail = [&](float* visout, float* objout) {
        sbmax2_k<<<16, 256, 0, stream>>>(sbV, smV, sbO, smO, NV, NO);
        AggP av{maskV, saV, sbV, smV, hTv, v1, hTv2, rs1, NV, tilesJV, tilesJV};
        AggP ao{maskO, saO, sbO, smO, hTo, o1, hTo2, nullptr, NO, tilesJO, tilesJO};
        agg2_k<<<G_AGG_V + G_AGG_O, 128, 0, stream>>>(av, ao, G_AGG_V);
        // vo: out[v] = rs1[v] * sum_o A[o][v] * o1[o][:]   (hTo2 unscaled)
        // ov: out[o] = rs2[o] * sum_v A[o][v] * (rs1[v] v1[v][:])  (hTv2 prescaled)
        CrossP cvo{A_OV, hTo2, rs1, ppV, NV, NO, tilesJV, tilesJO};
        CrossP cov{A_OV, hTv2, rs2, ppO, NO, NV, tilesJO, tilesJV};
        cross2_k<<<G_CR_VO + G_CR_OV, 128, 0, stream>>>(cvo, cov, G_CR_VO);
        MlpP mv{ppV, nullptr, 1, o2g_W1, o2g_b1, o2g_W2, o2g_b2, v1, visout, B * NV};
        MlpP mo{ppO, nullptr, 1, g2o_W1, g2o_b1, g2o_W2, g2o_b2, o1, objout, B * NO};
        mlp2_k<<<G_MLP_V + G_MLP_O, 128, 0, stream>>>(mv, mo, G_MLP_V);
    };

    // ---- layer 1 (Kv=512, Ko=32) ----
    {
        XprepP xv{vis_memory, XbfV, wav1a, wav1b, saV, sbV, B * NV};
        XprepP xo{obj_memory, XbfO, wao1a, wao1b, saO, sbO, B * NO};
        xprep2_k<512, 32><<<G_XP_V + G_XP_O, 256, 0, stream>>>(xv, xo, G_XP_V);
        GmfP gv{XbfV, WTv1, hTv, NV, tilesJV};
        GmfP go{XbfO, WTo1, hTo, NO, tilesJO};
        gmf2_k<512, 32><<<G_GMF_V + G_GMF_O, 256, 0, stream>>>(gv, go, G_GMF_V);
        tail(visb, objb);
    }
    // ---- layer 2 (Kv=Ko=128) ----
    {
        XprepP xv{visb, XbfV, wav2a, wav2b, saV, sbV, B * NV};
        XprepP xo{objb, XbfO, wao2a, wao2b, saO, sbO, B * NO};
        xprep2_k<128, 128><<<G_XP_V + G_XP_O, 256, 0, stream>>>(xv, xo, G_XP_V);
        GmfP gv{XbfV, WTv2, hTv, NV, tilesJV};
        GmfP go{XbfO, WTo2, hTo, NO, tilesJO};
        gmf2_k<128, 128><<<G_GMF_V + G_GMF_O, 256, 0, stream>>>(gv, go, G_GMF_V);
        tail(visb, objb);
    }

    // output projections
    float* vis_out = (float*)d_out;
    float* obj_out = vis_out + (size_t)B * NV * DV;
    linear_k<0, 1, 0><<<dim3((B * NV + 3) / 4, (DV + 255) / 256), 128, 0, stream>>>(
        visb, img_W, img_b, nullptr, vis_out, B * NV, HD, DV);
    linear_k<0, 1, 0><<<dim3((B * NO + 3) / 4, 1), 128, 0, stream>>>(
        objb, obj_W, obj_b, nullptr, obj_out, B * NO, HD, DO);
}